// Round 13
// baseline (173.610 us; speedup 1.0000x reference)
//
#include <hip/hip_runtime.h>
#include <cstddef>
#include <cstdint>

#define NB 4
#define CC 256
#define LL 4096
#define NG 32
#define CPG 8
#define NH 4
#define DH 64
#define PSPLIT 4194304   // fp16 partial-O elements per split: 16*4096*64

static constexpr float EPSV  = 1e-5f;
static constexpr float SCALE_Q = 0.125f * 1.4426950408889634f; // dh^-0.5 * log2(e)

typedef __attribute__((ext_vector_type(8))) short bf16x8;
typedef __attribute__((ext_vector_type(4))) float f32x4;
typedef _Float16 f16x8 __attribute__((ext_vector_type(8)));
typedef _Float16 f16x4 __attribute__((ext_vector_type(4)));
typedef __fp16  h16x2 __attribute__((ext_vector_type(2)));   // cvt_pkrtz native type

__device__ __forceinline__ short f2bf(float f) {
  unsigned u = __float_as_uint(f);
  unsigned r = (u + 0x7fffu + ((u >> 16) & 1u)) >> 16;
  return (short)r;
}
__device__ __forceinline__ short f2h(float f) {
  union { _Float16 h; short s; } u;
  u.h = (_Float16)f;
  return u.s;
}
// element offset of 16B chunk (8 elems) with XOR swizzle: row stride 64 elems
__device__ __forceinline__ int sw(int row, int chunk) {
  return row * 64 + ((chunk ^ (row & 7)) * 8);
}

// ---------------- fused GN stats + x^T f16 materialization + weight cvt ----------------
// blk<512: reduces 8ch x 1024l -> 2 partials AND writes raw x as f16 to xT [n][l][c]
//          (cast err ~5e-4, below the bf16-xn quantization at 4e-3).
// blk>=512: weight fp32 -> frag-major bf16/f16 (1KB/wave A-frag loads).
__global__ __launch_bounds__(256) void gnstats_wcvt(
    const float* __restrict__ x, float* __restrict__ pstat,
    _Float16* __restrict__ xT,
    const float* __restrict__ Wq, const float* __restrict__ Wk,
    const float* __restrict__ Wv, const float* __restrict__ Wp,
    short* __restrict__ wdst) {
  __shared__ float r1[4], r2[4];
  const int blk = blockIdx.x;
  if (blk < 512) {
    const int grp = blk >> 2, qtr = blk & 3;          // grp = n*32+g
    const int n = grp >> 5, g = grp & 31;
    const float* xp = x + (size_t)grp * CPG * LL + qtr * 1024 + threadIdx.x * 4;
    float s = 0.f, ss = 0.f;
    short ob[4][8] __attribute__((aligned(16)));
    #pragma unroll
    for (int cc = 0; cc < 8; ++cc) {
      const float4 v = *(const float4*)(xp + (size_t)cc * LL);
      s  += v.x + v.y + v.z + v.w;
      ss += v.x * v.x + v.y * v.y + v.z * v.z + v.w * v.w;
      ob[0][cc] = f2h(v.x); ob[1][cc] = f2h(v.y);
      ob[2][cc] = f2h(v.z); ob[3][cc] = f2h(v.w);
    }
    _Float16* op = xT + ((size_t)n * LL + qtr * 1024 + threadIdx.x * 4) * CC + g * CPG;
    #pragma unroll
    for (int j = 0; j < 4; ++j)
      *(uint4*)(op + (size_t)j * CC) = *(const uint4*)ob[j];
    #pragma unroll
    for (int off = 32; off; off >>= 1) {
      s  += __shfl_down(s, off);
      ss += __shfl_down(ss, off);
    }
    const int wid = threadIdx.x >> 6, lane = threadIdx.x & 63;
    if (lane == 0) { r1[wid] = s; r2[wid] = ss; }
    __syncthreads();
    if (threadIdx.x == 0) {
      float S = 0.f, SS = 0.f;
      #pragma unroll
      for (int w = 0; w < 4; ++w) { S += r1[w]; SS += r2[w]; }
      pstat[blk * 2]     = S;
      pstat[blk * 2 + 1] = SS;
    }
  } else {
    const int wblk = blk - 512;
    const int which = wblk >> 5;
    const float* src = (which == 0) ? Wq : (which == 1) ? Wk : (which == 2) ? Wv : Wp;
    const int base = (wblk & 31) * 2048 + threadIdx.x * 8;
    const float4 v0 = *(const float4*)(src + base);
    const float4 v1 = *(const float4*)(src + base + 4);
    short ob[8] __attribute__((aligned(16)));
    if (which < 3) {
      ob[0] = f2bf(v0.x); ob[1] = f2bf(v0.y); ob[2] = f2bf(v0.z); ob[3] = f2bf(v0.w);
      ob[4] = f2bf(v1.x); ob[5] = f2bf(v1.y); ob[6] = f2bf(v1.z); ob[7] = f2bf(v1.w);
    } else {
      ob[0] = f2h(v0.x); ob[1] = f2h(v0.y); ob[2] = f2h(v0.z); ob[3] = f2h(v0.w);
      ob[4] = f2h(v1.x); ob[5] = f2h(v1.y); ob[6] = f2h(v1.z); ob[7] = f2h(v1.w);
    }
    const int o = base >> 8, c = base & 255;
    const int dst = (((o >> 4) * 8 + (c >> 5)) * 64 + ((c >> 3) & 3) * 16 + (o & 15)) * 8;
    *(uint4*)(wdst + which * 65536 + dst) = *(const uint4*)ob;
  }
}

// ---------------- QKV MFMA GEMM v5: f16 xT input, linear LDS stage ----------------
// grid (2, 512) ot-major. Stage: read coalesced f16 xT rows, apply per-group
// affine, write LDS [l][c] LINEARLY (no transpose scatter). K-loop unchanged.
// Vo written PRE-PERMUTED: pos = l0 + 8*(lq>>2)+4*n0+(lq&3) (proven image).
__global__ __launch_bounds__(256) void qkv_gemm(
    const _Float16* __restrict__ xT, const float* __restrict__ gamma,
    const float* __restrict__ beta, const float* __restrict__ pstat,
    const short* __restrict__ Wqb, const short* __restrict__ Wkb,
    const short* __restrict__ Wvb,
    short* __restrict__ Qt, short* __restrict__ Kt, _Float16* __restrict__ Vo) {
  __shared__ __align__(16) short smem[64 * 136];   // 17408 B; stage 32x264 (16896 B), repack 2x32x136
  const int lt = blockIdx.y, ot2 = blockIdx.x;     // ot2 covers 128 output channels
  const int n = lt >> 7, l0 = (lt & 127) << 5;
  const int wave = threadIdx.x >> 6, lane = threadIdx.x & 63;
  const int lq = lane & 15, quad = lane >> 4;

  // ---- stage: f16 xT -> affine -> bf16 -> LDS (linear rows, stride 264) ----
  {
    const int ch = threadIdx.x & 31;               // c-chunk == group
    const int r0 = threadIdx.x >> 5;               // 0..7
    const int grp = n * NG + ch;
    float S = 0.f, SS = 0.f;
    #pragma unroll
    for (int w = 0; w < 4; ++w) {
      S  += pstat[(grp * 4 + w) * 2];
      SS += pstat[(grp * 4 + w) * 2 + 1];
    }
    const float mean = S / 32768.f;                // NE = 8*4096
    const float rstd = rsqrtf(SS / 32768.f - mean * mean + EPSV);
    float scl[8], shf[8];
    #pragma unroll
    for (int j = 0; j < 8; ++j) {
      scl[j] = rstd * gamma[ch * CPG + j];
      shf[j] = beta[ch * CPG + j] - mean * scl[j];
    }
    #pragma unroll
    for (int j = 0; j < 4; ++j) {
      const int row = r0 + 8 * j;                  // 0..31
      const f16x8 v = *(const f16x8*)(xT + ((size_t)(n * LL + l0 + row)) * CC + ch * 8);
      short ob[8] __attribute__((aligned(16)));
      #pragma unroll
      for (int e = 0; e < 8; ++e)
        ob[e] = f2bf((float)v[e] * scl[e] + shf[e]);
      *(uint4*)(smem + row * 264 + ch * 8) = *(const uint4*)ob;
    }
  }
  __syncthreads();

  // ---- MFMA K-loop: frag-major weights (coalesced), fb frags from LDS ----
  const int tb   = (ot2 * 8 + wave) * 8;           // tile base for w=0 (x512 elems)
  const int loff = lane * 8;
  const short* xl = smem + lq * 264 + quad * 8;

  const f32x4 z = {0.f, 0.f, 0.f, 0.f};
  f32x4 aq[2][2] = {{z, z}, {z, z}};
  f32x4 ak[2][2] = {{z, z}, {z, z}};
  f32x4 av[2][2] = {{z, z}, {z, z}};

  #pragma unroll
  for (int c5 = 0; c5 < 8; ++c5) {
    const int c0 = c5 * 32;
    const bf16x8 fq0 = *(const bf16x8*)(Wqb + (tb + c5) * 512 + loff);
    const bf16x8 fq1 = *(const bf16x8*)(Wqb + (tb + 32 + c5) * 512 + loff);
    const bf16x8 fk0 = *(const bf16x8*)(Wkb + (tb + c5) * 512 + loff);
    const bf16x8 fk1 = *(const bf16x8*)(Wkb + (tb + 32 + c5) * 512 + loff);
    const bf16x8 fv0 = *(const bf16x8*)(Wvb + (tb + c5) * 512 + loff);
    const bf16x8 fv1 = *(const bf16x8*)(Wvb + (tb + 32 + c5) * 512 + loff);
    #pragma unroll
    for (int n0 = 0; n0 < 2; ++n0) {
      const bf16x8 fb = *(const bf16x8*)(xl + (n0 * 16) * 264 + c0);
      aq[0][n0] = __builtin_amdgcn_mfma_f32_16x16x32_bf16(fq0, fb, aq[0][n0], 0, 0, 0);
      aq[1][n0] = __builtin_amdgcn_mfma_f32_16x16x32_bf16(fq1, fb, aq[1][n0], 0, 0, 0);
      ak[0][n0] = __builtin_amdgcn_mfma_f32_16x16x32_bf16(fk0, fb, ak[0][n0], 0, 0, 0);
      ak[1][n0] = __builtin_amdgcn_mfma_f32_16x16x32_bf16(fk1, fb, ak[1][n0], 0, 0, 0);
      av[0][n0] = __builtin_amdgcn_mfma_f32_16x16x32_bf16(fv0, fb, av[0][n0], 0, 0, 0);
      av[1][n0] = __builtin_amdgcn_mfma_f32_16x16x32_bf16(fv1, fb, av[1][n0], 0, 0, 0);
    }
  }

  // ---- V write: pre-permuted key position within the 64-block ----
  #pragma unroll
  for (int w = 0; w < 2; ++w) {
    const size_t hb = (size_t)(n * NH + ot2 * 2 + w);
    #pragma unroll
    for (int n0 = 0; n0 < 2; ++n0) {
      const int pos = l0 + 8 * (lq >> 2) + 4 * n0 + (lq & 3);
      #pragma unroll
      for (int r = 0; r < 4; ++r)
        Vo[(hb * DH + wave * 16 + quad * 4 + r) * LL + pos] = (_Float16)av[w][n0][r];
    }
  }

  // ---- reuse LDS for Qt/Kt repack: [32 l][136] per tensor ----
  __syncthreads();                                 // all xn reads done
  short* qt_l = smem;                              // [32][136]
  short* kt_l = smem + 32 * 136;                   // [32][136]
  #pragma unroll
  for (int w = 0; w < 2; ++w)
    #pragma unroll
    for (int n0 = 0; n0 < 2; ++n0)
      #pragma unroll
      for (int r = 0; r < 4; ++r) {
        const int row = n0 * 16 + lq;
        const int col = w * 64 + wave * 16 + quad * 4 + r;
        qt_l[row * 136 + col] = f2bf(aq[w][n0][r] * SCALE_Q);
        kt_l[row * 136 + col] = f2bf(ak[w][n0][r]);
      }
  __syncthreads();
  #pragma unroll
  for (int i = 0; i < 2; ++i) {
    const int u = threadIdx.x + i * 256;
    const int row = u >> 4, ch16 = u & 15;         // 32 rows x 16 chunks of 8 ch
    const int h = ot2 * 2 + (ch16 >> 3);
    const int d0 = (ch16 & 7) * 8;
    const size_t hb = (size_t)(n * NH + h);
    *(uint4*)(Qt + (hb * LL + l0 + row) * DH + d0) = *(const uint4*)&qt_l[row * 136 + ch16 * 8];
    *(uint4*)(Kt + (hb * LL + l0 + row) * DH + d0) = *(const uint4*)&kt_l[row * 136 + ch16 * 8];
  }
}

// ---------------- MFMA flash attention: 64 q/wave, perm-Vo uint4 staging ----------------
// grid (LL/256, NH*2, NB) = 512 blocks, block 256 (4 waves), 2 waves/SIMD (proven).
__global__ __launch_bounds__(256, 2) void attn_mfma_kernel(
    const short* __restrict__ Qt, const short* __restrict__ Kt,
    const _Float16* __restrict__ Vb, _Float16* __restrict__ Opart,
    float* __restrict__ lpart) {
  __shared__ __align__(16) short    k_lds[2][64 * 64];   // 8 KB each, swizzled
  __shared__ __align__(16) _Float16 v_lds[2][64 * 64];   // 8 KB each, swizzled (perm in global)

  const int t = threadIdx.x;
  const int wave = t >> 6, lane = t & 63;
  const int lq = lane & 15, quad = lane >> 4;
  const int l0 = blockIdx.x * 256;
  const int h = blockIdx.y >> 1, split = blockIdx.y & 1;
  const int n = blockIdx.z;
  const int kbase = split * 2048;
  const int R = n * NH + h;
  const size_t hb = (size_t)R * (size_t)LL * DH;
  const short* const Kp = Kt + hb;      // [key][d] bf16
  const _Float16* const Vp = Vb + hb;   // [d][perm(key)] f16

  const int qbase = l0 + wave * 64;
  bf16x8 qb[4][2];
  #pragma unroll
  for (int qf = 0; qf < 4; ++qf)
    #pragma unroll
    for (int c = 0; c < 2; ++c)
      qb[qf][c] = *(const bf16x8*)(Qt + hb + (size_t)(qbase + qf * 16 + lq) * DH + c * 32 + quad * 8);

  const f32x4 z = {0.f, 0.f, 0.f, 0.f};
  f32x4 o[4][4] = {{z, z, z, z}, {z, z, z, z}, {z, z, z, z}, {z, z, z, z}};
  f32x4 ol[4] = {z, z, z, z};

  f16x8 ones8;
  #pragma unroll
  for (int i = 0; i < 8; ++i) ones8[i] = (_Float16)1.0f;

  const int srow = t >> 3, sch = t & 7;   // staging: rows 0..31(+32), chunk 0..7

  // stage tile 0
  {
    *(uint4*)&k_lds[0][sw(srow, sch)]      = *(const uint4*)(Kp + (size_t)(kbase + srow) * DH + sch * 8);
    *(uint4*)&k_lds[0][sw(32 + srow, sch)] = *(const uint4*)(Kp + (size_t)(kbase + 32 + srow) * DH + sch * 8);
    *(uint4*)&v_lds[0][sw(srow, sch)]      = *(const uint4*)(Vp + (size_t)srow * LL + kbase + sch * 8);
    *(uint4*)&v_lds[0][sw(32 + srow, sch)] = *(const uint4*)(Vp + (size_t)(32 + srow) * LL + kbase + sch * 8);
  }
  __syncthreads();

  for (int kt = 0; kt < 32; ++kt) {
    const int cur = kt & 1;
    // prefetch next tile into regs (issue-early / write-late)
    uint4 kpre[2], vpre[2];
    if (kt < 31) {
      const int kpos = kbase + (kt + 1) * 64;
      kpre[0] = *(const uint4*)(Kp + (size_t)(kpos + srow) * DH + sch * 8);
      kpre[1] = *(const uint4*)(Kp + (size_t)(kpos + 32 + srow) * DH + sch * 8);
      vpre[0] = *(const uint4*)(Vp + (size_t)srow * LL + kpos + sch * 8);
      vpre[1] = *(const uint4*)(Vp + (size_t)(32 + srow) * LL + kpos + sch * 8);
    }
    const short* kb = k_lds[cur];
    const _Float16* vbuf = v_lds[cur];

    // ---- S^T = K·Q^T (bf16), p = exp2(s) -> f16 pack directly into A-frags ----
    union PU { f16x4 h4[2]; f16x8 h8; } af[2][4];
    #pragma unroll
    for (int mf = 0; mf < 4; ++mf) {
      const bf16x8 ka0 = *(const bf16x8*)&kb[sw(mf * 16 + lq, quad)];
      const bf16x8 ka1 = *(const bf16x8*)&kb[sw(mf * 16 + lq, 4 + quad)];
      #pragma unroll
      for (int qf = 0; qf < 4; ++qf) {
        f32x4 zz = {0.f, 0.f, 0.f, 0.f};
        zz = __builtin_amdgcn_mfma_f32_16x16x32_bf16(ka0, qb[qf][0], zz, 0, 0, 0);
        zz = __builtin_amdgcn_mfma_f32_16x16x32_bf16(ka1, qb[qf][1], zz, 0, 0, 0);
        union { h16x2 h2[2]; f16x4 h4; } u;
        u.h2[0] = __builtin_amdgcn_cvt_pkrtz(__builtin_amdgcn_exp2f(zz[0]),
                                             __builtin_amdgcn_exp2f(zz[1]));
        u.h2[1] = __builtin_amdgcn_cvt_pkrtz(__builtin_amdgcn_exp2f(zz[2]),
                                             __builtin_amdgcn_exp2f(zz[3]));
        af[mf >> 1][qf].h4[mf & 1] = u.h4;
      }
    }

    // ---- l-sum via ones-MFMA: D rows == o rows, in-lane ----
    #pragma unroll
    for (int qf = 0; qf < 4; ++qf) {
      ol[qf] = __builtin_amdgcn_mfma_f32_16x16x32_f16(af[0][qf].h8, ones8, ol[qf], 0, 0, 0);
      ol[qf] = __builtin_amdgcn_mfma_f32_16x16x32_f16(af[1][qf].h8, ones8, ol[qf], 0, 0, 0);
    }

    // ---- O += P·V: b128 V-frags, 0-conflict pattern ----
    #pragma unroll
    for (int df = 0; df < 4; ++df)
      #pragma unroll
      for (int cc = 0; cc < 2; ++cc) {
        const f16x8 vb8 = *(const f16x8*)&vbuf[sw(df * 16 + lq, cc * 4 + quad)];
        #pragma unroll
        for (int qf = 0; qf < 4; ++qf)
          o[qf][df] = __builtin_amdgcn_mfma_f32_16x16x32_f16(af[cc][qf].h8, vb8, o[qf][df], 0, 0, 0);
      }

    // ---- write prefetched tile to other buffer ----
    if (kt < 31) {
      const int nxt = 1 - cur;
      *(uint4*)&k_lds[nxt][sw(srow, sch)]      = kpre[0];
      *(uint4*)&k_lds[nxt][sw(32 + srow, sch)] = kpre[1];
      *(uint4*)&v_lds[nxt][sw(srow, sch)]      = vpre[0];
      *(uint4*)&v_lds[nxt][sw(32 + srow, sch)] = vpre[1];
      __syncthreads();
    }
  }

  // ---- epilogue: store partial l (rows match in-lane) + raw fp16 partial O ----
  const size_t pb = ((size_t)split * 16 + R) * (size_t)LL * DH;
  #pragma unroll
  for (int qf = 0; qf < 4; ++qf) {
    if (lq == 0) {
      #pragma unroll
      for (int r = 0; r < 4; ++r)
        lpart[((size_t)split * 16 + R) * LL + qbase + qf * 16 + quad * 4 + r] = ol[qf][r];
    }
    #pragma unroll
    for (int df = 0; df < 4; ++df)
      #pragma unroll
      for (int r = 0; r < 4; ++r) {
        const int q = qbase + qf * 16 + quad * 4 + r;
        Opart[pb + (size_t)q * DH + df * 16 + lq] = (_Float16)o[qf][df][r];
      }
  }
}

// ---------------- output projection v3: 32-l tiles, LDS-staged shared B ----------------
__global__ __launch_bounds__(256) void proj_gemm(
    const _Float16* __restrict__ Opart, const float* __restrict__ lpart,
    const _Float16* __restrict__ Wpf, const float* __restrict__ bp,
    float* __restrict__ out) {
  __shared__ __align__(16) _Float16 fb_lds[2][32 * 64];  // 4 KB each, sw()-swizzled
  const int lt = blockIdx.y, ot2 = blockIdx.x;   // ot2 covers 128 output channels
  const int n = lt >> 7, l0 = (lt & 127) << 5;
  const int wave = threadIdx.x >> 6, lane = threadIdx.x & 63;
  const int lq = lane & 15, quad = lane >> 4;
  const int t = threadIdx.x;
  const int qr = t >> 3, ch = t & 7;             // staging: q-row 0..31, d-chunk 0..7

  const int tb   = (ot2 * 8 + wave) * 8;         // frag tile base for w=0
  const int loff = lane * 8;

  auto stage_load = [&](int h, f16x8& dst) {
    const _Float16* Op = Opart + ((size_t)(n * NH + h) * LL + l0) * DH;
    const size_t rr = (size_t)(n * NH + h) * LL + l0 + qr;
    const _Float16 il = (_Float16)(1.0f / (lpart[rr] + lpart[rr + 16 * (size_t)LL]));
    const size_t e = (size_t)qr * DH + ch * 8;
    const f16x8 b0 = *(const f16x8*)(Op + e);
    const f16x8 b1 = *(const f16x8*)(Op + e + (size_t)PSPLIT);
    f16x8 sc8;
    #pragma unroll
    for (int i = 0; i < 8; ++i) sc8[i] = il;
    dst = (b0 + b1) * sc8;
  };

  {
    f16x8 f0;
    stage_load(0, f0);
    *(f16x8*)&fb_lds[0][sw(qr, ch)] = f0;
  }
  __syncthreads();

  const f32x4 z = {0.f, 0.f, 0.f, 0.f};
  f32x4 acc[2][2] = {{z, z}, {z, z}};
  for (int h = 0; h < NH; ++h) {
    const int cur = h & 1;
    f16x8 pre;
    if (h < NH - 1) stage_load(h + 1, pre);   // issue-early
    #pragma unroll
    for (int cw = 0; cw < 2; ++cw) {
      const int c5 = 2 * h + cw;
      const int c_idx = cw * 4 + quad;
      const f16x8 fa0 = *(const f16x8*)(Wpf + (tb + c5) * 512 + loff);
      const f16x8 fa1 = *(const f16x8*)(Wpf + (tb + 32 + c5) * 512 + loff);
      #pragma unroll
      for (int n0 = 0; n0 < 2; ++n0) {
        const f16x8 fb = *(const f16x8*)&fb_lds[cur][sw(n0 * 16 + lq, c_idx)];
        acc[0][n0] = __builtin_amdgcn_mfma_f32_16x16x32_f16(fa0, fb, acc[0][n0], 0, 0, 0);
        acc[1][n0] = __builtin_amdgcn_mfma_f32_16x16x32_f16(fa1, fb, acc[1][n0], 0, 0, 0);
      }
    }
    if (h < NH - 1) {                          // write-late
      *(f16x8*)&fb_lds[cur ^ 1][sw(qr, ch)] = pre;
      __syncthreads();
    }
  }

  #pragma unroll
  for (int w = 0; w < 2; ++w)
    #pragma unroll
    for (int r = 0; r < 4; ++r) {
      const int oo = ot2 * 128 + w * 64 + wave * 16 + quad * 4 + r;
      const float bias = bp[oo];
      #pragma unroll
      for (int n0 = 0; n0 < 2; ++n0)
        out[((size_t)n * CC + oo) * LL + l0 + n0 * 16 + lq] = acc[w][n0][r] + bias;
    }
}

extern "C" void kernel_launch(void* const* d_in, const int* in_sizes, int n_in,
                              void* d_out, int out_size, void* d_ws, size_t ws_size,
                              hipStream_t stream) {
  const float* x     = (const float*)d_in[0];
  const float* gamma = (const float*)d_in[1];
  const float* beta  = (const float*)d_in[2];
  const float* Wq    = (const float*)d_in[3];
  const float* Wk    = (const float*)d_in[4];
  const float* Wv    = (const float*)d_in[5];
  const float* Wp    = (const float*)d_in[6];
  const float* bp    = (const float*)d_in[7];
  float* out = (float*)d_out;

  const size_t S = (size_t)NB * CC * LL;  // 4,194,304
  short*     Qt  = (short*)d_ws;          // bf16 [n,h][l][d]
  short*     Kt  = Qt + S;
  _Float16*  Vo  = (_Float16*)(Kt + S);   // f16 [n,h][d][perm(l)]
  short*     Wb  = (short*)(Vo + S);      // 4 x 65536 (bf16 x3, f16 x1), frag-major
  _Float16*  Opart = (_Float16*)(Wb + 4 * 65536);  // 2 x 8 MB fp16
  float*     lpart = (float*)(Opart + 2 * (size_t)PSPLIT); // 2 x 256 KB fp32
  float*     pstat = lpart + 2 * 16 * (size_t)LL;  // 1024 floats GN partials
  _Float16*  xT    = (_Float16*)(pstat + 1024);    // f16 [n][l][c], 8.4 MB

  gnstats_wcvt<<<640,                 256, 0, stream>>>(x, pstat, xT, Wq, Wk, Wv, Wp, Wb);
  qkv_gemm   <<<dim3(2, 512),         256, 0, stream>>>(xT, gamma, beta, pstat,
                 Wb, Wb + 65536, Wb + 131072, Qt, Kt, Vo);
  attn_mfma_kernel<<<dim3(LL/256, NH*2, NB), 256, 0, stream>>>(Qt, Kt, Vo, Opart, lpart);
  proj_gemm  <<<dim3(2, 512),         256, 0, stream>>>(Opart, lpart,
                 (const _Float16*)(Wb + 196608), bp, out);
}

// Round 14
// 170.391 us; speedup vs baseline: 1.0189x; 1.0189x over previous
//
#include <hip/hip_runtime.h>
#include <cstddef>
#include <cstdint>

#define NB 4
#define CC 256
#define LL 4096
#define NG 32
#define CPG 8
#define NH 4
#define DH 64
#define PSPLIT 4194304   // fp16 partial-O elements per split: 16*4096*64

static constexpr float EPSV  = 1e-5f;
static constexpr float SCALE_Q = 0.125f * 1.4426950408889634f; // dh^-0.5 * log2(e)

typedef __attribute__((ext_vector_type(8))) short bf16x8;
typedef __attribute__((ext_vector_type(4))) float f32x4;
typedef _Float16 f16x8 __attribute__((ext_vector_type(8)));
typedef _Float16 f16x4 __attribute__((ext_vector_type(4)));
typedef __fp16  h16x2 __attribute__((ext_vector_type(2)));   // cvt_pkrtz native type

__device__ __forceinline__ short f2bf(float f) {
  unsigned u = __float_as_uint(f);
  unsigned r = (u + 0x7fffu + ((u >> 16) & 1u)) >> 16;
  return (short)r;
}
__device__ __forceinline__ short f2h(float f) {
  union { _Float16 h; short s; } u;
  u.h = (_Float16)f;
  return u.s;
}
// element offset of 16B chunk (8 elems) with XOR swizzle: row stride 64 elems
__device__ __forceinline__ int sw(int row, int chunk) {
  return row * 64 + ((chunk ^ (row & 7)) * 8);
}

// ---------------- fused GroupNorm stats (512 blocks) + weight cvt (128 blocks) ----------------
// wcvt emits FRAGMENT-MAJOR layout: tile t = o/16, c5 = c/32; element at
// ((t*8+c5)*64 + quad*16 + row)*8 + e. A-frag load = one 1KB wave transaction.
__global__ __launch_bounds__(256) void gnstats_wcvt(
    const float* __restrict__ x, float* __restrict__ pstat,
    const float* __restrict__ Wq, const float* __restrict__ Wk,
    const float* __restrict__ Wv, const float* __restrict__ Wp,
    short* __restrict__ wdst) {
  __shared__ float r1[4], r2[4];
  const int blk = blockIdx.x;
  if (blk < 512) {
    const int grp = blk >> 2, qtr = blk & 3;          // grp = n*32+g
    const float* xp = x + (size_t)grp * CPG * LL + qtr * 1024 + threadIdx.x * 4;
    float s = 0.f, ss = 0.f;
    #pragma unroll
    for (int cc = 0; cc < 8; ++cc) {
      const float4 v = *(const float4*)(xp + (size_t)cc * LL);
      s  += v.x + v.y + v.z + v.w;
      ss += v.x * v.x + v.y * v.y + v.z * v.z + v.w * v.w;
    }
    #pragma unroll
    for (int off = 32; off; off >>= 1) {
      s  += __shfl_down(s, off);
      ss += __shfl_down(ss, off);
    }
    const int wid = threadIdx.x >> 6, lane = threadIdx.x & 63;
    if (lane == 0) { r1[wid] = s; r2[wid] = ss; }
    __syncthreads();
    if (threadIdx.x == 0) {
      float S = 0.f, SS = 0.f;
      #pragma unroll
      for (int w = 0; w < 4; ++w) { S += r1[w]; SS += r2[w]; }
      pstat[blk * 2]     = S;
      pstat[blk * 2 + 1] = SS;
    }
  } else {
    const int wblk = blk - 512;
    const int which = wblk >> 5;
    const float* src = (which == 0) ? Wq : (which == 1) ? Wk : (which == 2) ? Wv : Wp;
    const int base = (wblk & 31) * 2048 + threadIdx.x * 8;
    const float4 v0 = *(const float4*)(src + base);
    const float4 v1 = *(const float4*)(src + base + 4);
    short ob[8] __attribute__((aligned(16)));
    if (which < 3) {
      ob[0] = f2bf(v0.x); ob[1] = f2bf(v0.y); ob[2] = f2bf(v0.z); ob[3] = f2bf(v0.w);
      ob[4] = f2bf(v1.x); ob[5] = f2bf(v1.y); ob[6] = f2bf(v1.z); ob[7] = f2bf(v1.w);
    } else {
      ob[0] = f2h(v0.x); ob[1] = f2h(v0.y); ob[2] = f2h(v0.z); ob[3] = f2h(v0.w);
      ob[4] = f2h(v1.x); ob[5] = f2h(v1.y); ob[6] = f2h(v1.z); ob[7] = f2h(v1.w);
    }
    const int o = base >> 8, c = base & 255;
    const int dst = (((o >> 4) * 8 + (c >> 5)) * 64 + ((c >> 3) & 3) * 16 + (o & 15)) * 8;
    *(uint4*)(wdst + which * 65536 + dst) = *(const uint4*)ob;
  }
}

// ---------------- QKV MFMA GEMM (round-11 best body, 64-l tiles) ----------------
// grid (2, 256) ot-major: consecutive blocks share the x-tile -> L2-hit staging.
// Vo written PRE-PERMUTED per round-4 verified formula (64-l):
//   pos = l0 + 32*(n0>>1) + 8*(lq>>2) + 4*(n0&1) + (lq&3)
// so attn stages V with single uint4 loads reproducing the proven LDS image.
__global__ __launch_bounds__(256) void qkv_gemm(
    const float* __restrict__ x, const float* __restrict__ gamma,
    const float* __restrict__ beta, const float* __restrict__ pstat,
    const short* __restrict__ Wqb, const short* __restrict__ Wkb,
    const short* __restrict__ Wvb,
    short* __restrict__ Qt, short* __restrict__ Kt, _Float16* __restrict__ Vo) {
  __shared__ __align__(16) short smem[64 * 272];   // xn tile (stride 264), later qt/kt (stride 136)
  const int lt = blockIdx.y, ot2 = blockIdx.x;     // ot2 covers 128 output channels
  const int n = lt >> 6, l0 = (lt & 63) << 6;
  const int wave = threadIdx.x >> 6, lane = threadIdx.x & 63;
  const int lq = lane & 15, quad = lane >> 4;

  // ---- stage: normalize + bf16 + transpose into LDS (once per block) ----
  #pragma unroll
  for (int i = 0; i < 2; ++i) {
    const int u = threadIdx.x + i * 256;
    const int cc = u >> 4, l4 = u & 15;              // cc = c-chunk == group
    const int grp = n * NG + cc;
    float S = 0.f, SS = 0.f;
    #pragma unroll
    for (int w = 0; w < 4; ++w) {
      S  += pstat[(grp * 4 + w) * 2];
      SS += pstat[(grp * 4 + w) * 2 + 1];
    }
    const float mean = S / 32768.f;                  // NE = 8*4096
    const float rstd = rsqrtf(SS / 32768.f - mean * mean + EPSV);
    const float* xp = x + (size_t)(n * CC + cc * CPG) * LL + l0 + l4 * 4;
    short ob[4][8] __attribute__((aligned(16)));
    #pragma unroll
    for (int j = 0; j < 8; ++j) {
      const float scl = rstd * gamma[cc * CPG + j];
      const float shf = beta[cc * CPG + j] - mean * scl;
      const float4 v = *(const float4*)(xp + (size_t)j * LL);
      ob[0][j] = f2bf(v.x * scl + shf);
      ob[1][j] = f2bf(v.y * scl + shf);
      ob[2][j] = f2bf(v.z * scl + shf);
      ob[3][j] = f2bf(v.w * scl + shf);
    }
    short* dst = smem + (l4 * 4) * 264 + cc * 8;
    #pragma unroll
    for (int jj = 0; jj < 4; ++jj)
      *(uint4*)(dst + jj * 264) = *(const uint4*)ob[jj];
  }
  __syncthreads();

  // ---- MFMA K-loop: frag-major weights (coalesced), fb frags from LDS ----
  const int tb   = (ot2 * 8 + wave) * 8;             // tile base for w=0 (x512 elems)
  const int loff = lane * 8;
  const short* xl = smem + lq * 264 + quad * 8;

  const f32x4 z = {0.f, 0.f, 0.f, 0.f};
  f32x4 aq[2][4] = {{z, z, z, z}, {z, z, z, z}};
  f32x4 ak[2][4] = {{z, z, z, z}, {z, z, z, z}};
  f32x4 av[2][4] = {{z, z, z, z}, {z, z, z, z}};

  #pragma unroll
  for (int c5 = 0; c5 < 8; ++c5) {
    const int c0 = c5 * 32;
    const bf16x8 fq0 = *(const bf16x8*)(Wqb + (tb + c5) * 512 + loff);
    const bf16x8 fq1 = *(const bf16x8*)(Wqb + (tb + 32 + c5) * 512 + loff);
    const bf16x8 fk0 = *(const bf16x8*)(Wkb + (tb + c5) * 512 + loff);
    const bf16x8 fk1 = *(const bf16x8*)(Wkb + (tb + 32 + c5) * 512 + loff);
    const bf16x8 fv0 = *(const bf16x8*)(Wvb + (tb + c5) * 512 + loff);
    const bf16x8 fv1 = *(const bf16x8*)(Wvb + (tb + 32 + c5) * 512 + loff);
    #pragma unroll
    for (int n0 = 0; n0 < 4; ++n0) {
      const bf16x8 fb = *(const bf16x8*)(xl + (n0 * 16) * 264 + c0);
      aq[0][n0] = __builtin_amdgcn_mfma_f32_16x16x32_bf16(fq0, fb, aq[0][n0], 0, 0, 0);
      aq[1][n0] = __builtin_amdgcn_mfma_f32_16x16x32_bf16(fq1, fb, aq[1][n0], 0, 0, 0);
      ak[0][n0] = __builtin_amdgcn_mfma_f32_16x16x32_bf16(fk0, fb, ak[0][n0], 0, 0, 0);
      ak[1][n0] = __builtin_amdgcn_mfma_f32_16x16x32_bf16(fk1, fb, ak[1][n0], 0, 0, 0);
      av[0][n0] = __builtin_amdgcn_mfma_f32_16x16x32_bf16(fv0, fb, av[0][n0], 0, 0, 0);
      av[1][n0] = __builtin_amdgcn_mfma_f32_16x16x32_bf16(fv1, fb, av[1][n0], 0, 0, 0);
    }
  }

  // ---- V write: pre-permuted key position within the 64-block (round-4 verified) ----
  #pragma unroll
  for (int w = 0; w < 2; ++w) {
    const size_t hb = (size_t)(n * NH + ot2 * 2 + w);
    #pragma unroll
    for (int n0 = 0; n0 < 4; ++n0) {
      const int pos = l0 + 32 * (n0 >> 1) + 8 * (lq >> 2) + 4 * (n0 & 1) + (lq & 3);
      #pragma unroll
      for (int r = 0; r < 4; ++r)
        Vo[(hb * DH + wave * 16 + quad * 4 + r) * LL + pos] = (_Float16)av[w][n0][r];
    }
  }

  // ---- reuse LDS for Qt/Kt repack: [64 l][136] per tensor (16B-aligned rows) ----
  __syncthreads();                                   // all xn reads done
  short* qt_l = smem;                                // [64][136]
  short* kt_l = smem + 64 * 136;                     // [64][136]
  #pragma unroll
  for (int w = 0; w < 2; ++w)
    #pragma unroll
    for (int n0 = 0; n0 < 4; ++n0)
      #pragma unroll
      for (int r = 0; r < 4; ++r) {
        const int row = n0 * 16 + lq;
        const int col = w * 64 + wave * 16 + quad * 4 + r;
        qt_l[row * 136 + col] = f2bf(aq[w][n0][r] * SCALE_Q);
        kt_l[row * 136 + col] = f2bf(ak[w][n0][r]);
      }
  __syncthreads();
  #pragma unroll
  for (int i = 0; i < 4; ++i) {
    const int u = threadIdx.x + i * 256;
    const int row = u >> 4, ch16 = u & 15;           // 64 rows x 16 chunks of 8 ch
    const int h = ot2 * 2 + (ch16 >> 3);
    const int d0 = (ch16 & 7) * 8;
    const size_t hb = (size_t)(n * NH + h);
    *(uint4*)(Qt + (hb * LL + l0 + row) * DH + d0) = *(const uint4*)&qt_l[row * 136 + ch16 * 8];
    *(uint4*)(Kt + (hb * LL + l0 + row) * DH + d0) = *(const uint4*)&kt_l[row * 136 + ch16 * 8];
  }
}

// ---------------- MFMA flash attention: 64 q/wave, perm-Vo uint4 staging ----------------
// grid (LL/256, NH*2, NB) = 512 blocks, block 256 (4 waves), 2 waves/SIMD (proven).
// Vo pre-permuted by qkv -> V staging is single uint4 per row, reproducing the
// round-0 LDS image exactly; all frag reads unchanged. (round-12 verified body)
__global__ __launch_bounds__(256, 2) void attn_mfma_kernel(
    const short* __restrict__ Qt, const short* __restrict__ Kt,
    const _Float16* __restrict__ Vb, _Float16* __restrict__ Opart,
    float* __restrict__ lpart) {
  __shared__ __align__(16) short    k_lds[2][64 * 64];   // 8 KB each, swizzled
  __shared__ __align__(16) _Float16 v_lds[2][64 * 64];   // 8 KB each, swizzled (perm in global)

  const int t = threadIdx.x;
  const int wave = t >> 6, lane = t & 63;
  const int lq = lane & 15, quad = lane >> 4;
  const int l0 = blockIdx.x * 256;
  const int h = blockIdx.y >> 1, split = blockIdx.y & 1;
  const int n = blockIdx.z;
  const int kbase = split * 2048;
  const int R = n * NH + h;
  const size_t hb = (size_t)R * (size_t)LL * DH;
  const short* const Kp = Kt + hb;      // [key][d] bf16
  const _Float16* const Vp = Vb + hb;   // [d][perm(key)] f16

  const int qbase = l0 + wave * 64;
  bf16x8 qb[4][2];
  #pragma unroll
  for (int qf = 0; qf < 4; ++qf)
    #pragma unroll
    for (int c = 0; c < 2; ++c)
      qb[qf][c] = *(const bf16x8*)(Qt + hb + (size_t)(qbase + qf * 16 + lq) * DH + c * 32 + quad * 8);

  const f32x4 z = {0.f, 0.f, 0.f, 0.f};
  f32x4 o[4][4] = {{z, z, z, z}, {z, z, z, z}, {z, z, z, z}, {z, z, z, z}};
  f32x4 ol[4] = {z, z, z, z};

  f16x8 ones8;
  #pragma unroll
  for (int i = 0; i < 8; ++i) ones8[i] = (_Float16)1.0f;

  const int srow = t >> 3, sch = t & 7;   // staging: rows 0..31(+32), chunk 0..7

  // stage tile 0
  {
    *(uint4*)&k_lds[0][sw(srow, sch)]      = *(const uint4*)(Kp + (size_t)(kbase + srow) * DH + sch * 8);
    *(uint4*)&k_lds[0][sw(32 + srow, sch)] = *(const uint4*)(Kp + (size_t)(kbase + 32 + srow) * DH + sch * 8);
    *(uint4*)&v_lds[0][sw(srow, sch)]      = *(const uint4*)(Vp + (size_t)srow * LL + kbase + sch * 8);
    *(uint4*)&v_lds[0][sw(32 + srow, sch)] = *(const uint4*)(Vp + (size_t)(32 + srow) * LL + kbase + sch * 8);
  }
  __syncthreads();

  for (int kt = 0; kt < 32; ++kt) {
    const int cur = kt & 1;
    // prefetch next tile into regs (issue-early / write-late)
    uint4 kpre[2], vpre[2];
    if (kt < 31) {
      const int kpos = kbase + (kt + 1) * 64;
      kpre[0] = *(const uint4*)(Kp + (size_t)(kpos + srow) * DH + sch * 8);
      kpre[1] = *(const uint4*)(Kp + (size_t)(kpos + 32 + srow) * DH + sch * 8);
      vpre[0] = *(const uint4*)(Vp + (size_t)srow * LL + kpos + sch * 8);
      vpre[1] = *(const uint4*)(Vp + (size_t)(32 + srow) * LL + kpos + sch * 8);
    }
    const short* kb = k_lds[cur];
    const _Float16* vbuf = v_lds[cur];

    // ---- S^T = K·Q^T (bf16), p = exp2(s) -> f16 pack directly into A-frags ----
    union PU { f16x4 h4[2]; f16x8 h8; } af[2][4];
    #pragma unroll
    for (int mf = 0; mf < 4; ++mf) {
      const bf16x8 ka0 = *(const bf16x8*)&kb[sw(mf * 16 + lq, quad)];
      const bf16x8 ka1 = *(const bf16x8*)&kb[sw(mf * 16 + lq, 4 + quad)];
      #pragma unroll
      for (int qf = 0; qf < 4; ++qf) {
        f32x4 zz = {0.f, 0.f, 0.f, 0.f};
        zz = __builtin_amdgcn_mfma_f32_16x16x32_bf16(ka0, qb[qf][0], zz, 0, 0, 0);
        zz = __builtin_amdgcn_mfma_f32_16x16x32_bf16(ka1, qb[qf][1], zz, 0, 0, 0);
        union { h16x2 h2[2]; f16x4 h4; } u;
        u.h2[0] = __builtin_amdgcn_cvt_pkrtz(__builtin_amdgcn_exp2f(zz[0]),
                                             __builtin_amdgcn_exp2f(zz[1]));
        u.h2[1] = __builtin_amdgcn_cvt_pkrtz(__builtin_amdgcn_exp2f(zz[2]),
                                             __builtin_amdgcn_exp2f(zz[3]));
        af[mf >> 1][qf].h4[mf & 1] = u.h4;
      }
    }

    // ---- l-sum via ones-MFMA: D rows == o rows, in-lane ----
    #pragma unroll
    for (int qf = 0; qf < 4; ++qf) {
      ol[qf] = __builtin_amdgcn_mfma_f32_16x16x32_f16(af[0][qf].h8, ones8, ol[qf], 0, 0, 0);
      ol[qf] = __builtin_amdgcn_mfma_f32_16x16x32_f16(af[1][qf].h8, ones8, ol[qf], 0, 0, 0);
    }

    // ---- O += P·V: b128 V-frags, 0-conflict pattern ----
    #pragma unroll
    for (int df = 0; df < 4; ++df)
      #pragma unroll
      for (int cc = 0; cc < 2; ++cc) {
        const f16x8 vb8 = *(const f16x8*)&vbuf[sw(df * 16 + lq, cc * 4 + quad)];
        #pragma unroll
        for (int qf = 0; qf < 4; ++qf)
          o[qf][df] = __builtin_amdgcn_mfma_f32_16x16x32_f16(af[cc][qf].h8, vb8, o[qf][df], 0, 0, 0);
      }

    // ---- write prefetched tile to other buffer ----
    if (kt < 31) {
      const int nxt = 1 - cur;
      *(uint4*)&k_lds[nxt][sw(srow, sch)]      = kpre[0];
      *(uint4*)&k_lds[nxt][sw(32 + srow, sch)] = kpre[1];
      *(uint4*)&v_lds[nxt][sw(srow, sch)]      = vpre[0];
      *(uint4*)&v_lds[nxt][sw(32 + srow, sch)] = vpre[1];
      __syncthreads();
    }
  }

  // ---- epilogue: store partial l (rows match in-lane) + raw fp16 partial O ----
  const size_t pb = ((size_t)split * 16 + R) * (size_t)LL * DH;
  #pragma unroll
  for (int qf = 0; qf < 4; ++qf) {
    if (lq == 0) {
      #pragma unroll
      for (int r = 0; r < 4; ++r)
        lpart[((size_t)split * 16 + R) * LL + qbase + qf * 16 + quad * 4 + r] = ol[qf][r];
    }
    #pragma unroll
    for (int df = 0; df < 4; ++df)
      #pragma unroll
      for (int r = 0; r < 4; ++r) {
        const int q = qbase + qf * 16 + quad * 4 + r;
        Opart[pb + (size_t)q * DH + df * 16 + lq] = (_Float16)o[qf][df][r];
      }
  }
}

// ---------------- output projection (round-11 best body): LDS-staged shared B ----------------
// grid (2, 256) ot-major. fb (normalized O) is IDENTICAL for all 4 waves -> stage
// it once per block per head into LDS, double-buffered across the 4 heads.
__global__ __launch_bounds__(256) void proj_gemm(
    const _Float16* __restrict__ Opart, const float* __restrict__ lpart,
    const _Float16* __restrict__ Wpf, const float* __restrict__ bp,
    float* __restrict__ out) {
  __shared__ __align__(16) _Float16 fb_lds[2][64 * 64];  // 8 KB each, sw()-swizzled
  const int lt = blockIdx.y, ot2 = blockIdx.x;   // ot2 covers 128 output channels
  const int n = lt >> 6, l0 = (lt & 63) << 6;
  const int wave = threadIdx.x >> 6, lane = threadIdx.x & 63;
  const int lq = lane & 15, quad = lane >> 4;
  const int t = threadIdx.x;
  const int qr = t >> 3, ch = t & 7;             // staging: q-row 0..31(+32), d-chunk 0..7

  const int tb   = (ot2 * 8 + wave) * 8;         // frag tile base for w=0
  const int loff = lane * 8;

  // stage head h into buf: fb = (b0 + b1) * (f16)(1/l)
  auto stage = [&](int buf, int h) {
    const _Float16* Op = Opart + ((size_t)(n * NH + h) * LL + l0) * DH;
    #pragma unroll
    for (int half = 0; half < 2; ++half) {
      const int q = half * 32 + qr;
      const size_t rr = (size_t)(n * NH + h) * LL + l0 + q;
      const _Float16 il = (_Float16)(1.0f / (lpart[rr] + lpart[rr + 16 * (size_t)LL]));
      const size_t e = (size_t)q * DH + ch * 8;
      const f16x8 b0 = *(const f16x8*)(Op + e);
      const f16x8 b1 = *(const f16x8*)(Op + e + (size_t)PSPLIT);
      f16x8 sc8;
      #pragma unroll
      for (int i = 0; i < 8; ++i) sc8[i] = il;
      const f16x8 fbn = (b0 + b1) * sc8;
      *(f16x8*)&fb_lds[buf][sw(q, ch)] = fbn;
    }
  };

  stage(0, 0);
  __syncthreads();

  const f32x4 z = {0.f, 0.f, 0.f, 0.f};
  f32x4 acc[2][4] = {{z, z, z, z}, {z, z, z, z}};
  for (int h = 0; h < NH; ++h) {
    const int cur = h & 1;
    // prefetch next head into regs (issue-early), write-late after compute
    f16x8 pre[2];
    if (h < NH - 1) {
      const _Float16* Op = Opart + ((size_t)(n * NH + h + 1) * LL + l0) * DH;
      #pragma unroll
      for (int half = 0; half < 2; ++half) {
        const int q = half * 32 + qr;
        const size_t rr = (size_t)(n * NH + h + 1) * LL + l0 + q;
        const _Float16 il = (_Float16)(1.0f / (lpart[rr] + lpart[rr + 16 * (size_t)LL]));
        const size_t e = (size_t)q * DH + ch * 8;
        const f16x8 b0 = *(const f16x8*)(Op + e);
        const f16x8 b1 = *(const f16x8*)(Op + e + (size_t)PSPLIT);
        f16x8 sc8;
        #pragma unroll
        for (int i = 0; i < 8; ++i) sc8[i] = il;
        pre[half] = (b0 + b1) * sc8;
      }
    }
    // compute the two c5 slices of this head from LDS
    #pragma unroll
    for (int cw = 0; cw < 2; ++cw) {
      const int c5 = 2 * h + cw;
      const int c_idx = cw * 4 + quad;
      const f16x8 fa0 = *(const f16x8*)(Wpf + (tb + c5) * 512 + loff);
      const f16x8 fa1 = *(const f16x8*)(Wpf + (tb + 32 + c5) * 512 + loff);
      #pragma unroll
      for (int n0 = 0; n0 < 4; ++n0) {
        const f16x8 fb = *(const f16x8*)&fb_lds[cur][sw(n0 * 16 + lq, c_idx)];
        acc[0][n0] = __builtin_amdgcn_mfma_f32_16x16x32_f16(fa0, fb, acc[0][n0], 0, 0, 0);
        acc[1][n0] = __builtin_amdgcn_mfma_f32_16x16x32_f16(fa1, fb, acc[1][n0], 0, 0, 0);
      }
    }
    if (h < NH - 1) {
      #pragma unroll
      for (int half = 0; half < 2; ++half)
        *(f16x8*)&fb_lds[cur ^ 1][sw(half * 32 + qr, ch)] = pre[half];
      __syncthreads();
    }
  }

  #pragma unroll
  for (int w = 0; w < 2; ++w)
    #pragma unroll
    for (int r = 0; r < 4; ++r) {
      const int oo = ot2 * 128 + w * 64 + wave * 16 + quad * 4 + r;
      const float bias = bp[oo];
      #pragma unroll
      for (int n0 = 0; n0 < 4; ++n0)
        out[((size_t)n * CC + oo) * LL + l0 + n0 * 16 + lq] = acc[w][n0][r] + bias;
    }
}

extern "C" void kernel_launch(void* const* d_in, const int* in_sizes, int n_in,
                              void* d_out, int out_size, void* d_ws, size_t ws_size,
                              hipStream_t stream) {
  const float* x     = (const float*)d_in[0];
  const float* gamma = (const float*)d_in[1];
  const float* beta  = (const float*)d_in[2];
  const float* Wq    = (const float*)d_in[3];
  const float* Wk    = (const float*)d_in[4];
  const float* Wv    = (const float*)d_in[5];
  const float* Wp    = (const float*)d_in[6];
  const float* bp    = (const float*)d_in[7];
  float* out = (float*)d_out;

  const size_t S = (size_t)NB * CC * LL;  // 4,194,304
  short*     Qt  = (short*)d_ws;          // bf16 [n,h][l][d]
  short*     Kt  = Qt + S;
  _Float16*  Vo  = (_Float16*)(Kt + S);   // f16 [n,h][d][perm(l)]
  short*     Wb  = (short*)(Vo + S);      // 4 x 65536 (bf16 x3, f16 x1), frag-major
  _Float16*  Opart = (_Float16*)(Wb + 4 * 65536);  // 2 x 8 MB fp16
  float*     lpart = (float*)(Opart + 2 * (size_t)PSPLIT); // 2 x 256 KB fp32
  float*     pstat = lpart + 2 * 16 * (size_t)LL;  // 1024 floats GN partials

  gnstats_wcvt<<<640,                 256, 0, stream>>>(x, pstat, Wq, Wk, Wv, Wp, Wb);
  qkv_gemm   <<<dim3(2, 256),         256, 0, stream>>>(x, gamma, beta, pstat,
                 Wb, Wb + 65536, Wb + 131072, Qt, Kt, Vo);
  attn_mfma_kernel<<<dim3(LL/256, NH*2, NB), 256, 0, stream>>>(Qt, Kt, Vo, Opart, lpart);
  proj_gemm  <<<dim3(2, 256),         256, 0, stream>>>(Opart, lpart,
                 (const _Float16*)(Wb + 196608), bp, out);
}

// Round 16
// 169.387 us; speedup vs baseline: 1.0249x; 1.0059x over previous
//
#include <hip/hip_runtime.h>
#include <cstddef>
#include <cstdint>

#define NB 4
#define CC 256
#define LL 4096
#define NG 32
#define CPG 8
#define NH 4
#define DH 64
#define PSPLIT 4194304   // fp16 partial-O elements per split: 16*4096*64

static constexpr float EPSV  = 1e-5f;
static constexpr float SCALE_Q = 0.125f * 1.4426950408889634f; // dh^-0.5 * log2(e)

typedef __attribute__((ext_vector_type(8))) short bf16x8;
typedef __attribute__((ext_vector_type(4))) float f32x4;
typedef _Float16 f16x8 __attribute__((ext_vector_type(8)));
typedef _Float16 f16x4 __attribute__((ext_vector_type(4)));
typedef __fp16  h16x2 __attribute__((ext_vector_type(2)));   // cvt_pkrtz native type

__device__ __forceinline__ short f2bf(float f) {
  unsigned u = __float_as_uint(f);
  unsigned r = (u + 0x7fffu + ((u >> 16) & 1u)) >> 16;
  return (short)r;
}
__device__ __forceinline__ short f2h(float f) {
  union { _Float16 h; short s; } u;
  u.h = (_Float16)f;
  return u.s;
}
// element offset of 16B chunk (8 elems) with XOR swizzle: row stride 64 elems
__device__ __forceinline__ int sw(int row, int chunk) {
  return row * 64 + ((chunk ^ (row & 7)) * 8);
}

// ---------------- fused GroupNorm stats (512 blocks) + weight cvt (128 blocks) ----------------
// wcvt emits FRAGMENT-MAJOR layout: tile t = o/16, c5 = c/32; element at
// ((t*8+c5)*64 + quad*16 + row)*8 + e. A-frag load = one 1KB wave transaction.
__global__ __launch_bounds__(256) void gnstats_wcvt(
    const float* __restrict__ x, float* __restrict__ pstat,
    const float* __restrict__ Wq, const float* __restrict__ Wk,
    const float* __restrict__ Wv, const float* __restrict__ Wp,
    short* __restrict__ wdst) {
  __shared__ float r1[4], r2[4];
  const int blk = blockIdx.x;
  if (blk < 512) {
    const int grp = blk >> 2, qtr = blk & 3;          // grp = n*32+g
    const float* xp = x + (size_t)grp * CPG * LL + qtr * 1024 + threadIdx.x * 4;
    float s = 0.f, ss = 0.f;
    #pragma unroll
    for (int cc = 0; cc < 8; ++cc) {
      const float4 v = *(const float4*)(xp + (size_t)cc * LL);
      s  += v.x + v.y + v.z + v.w;
      ss += v.x * v.x + v.y * v.y + v.z * v.z + v.w * v.w;
    }
    #pragma unroll
    for (int off = 32; off; off >>= 1) {
      s  += __shfl_down(s, off);
      ss += __shfl_down(ss, off);
    }
    const int wid = threadIdx.x >> 6, lane = threadIdx.x & 63;
    if (lane == 0) { r1[wid] = s; r2[wid] = ss; }
    __syncthreads();
    if (threadIdx.x == 0) {
      float S = 0.f, SS = 0.f;
      #pragma unroll
      for (int w = 0; w < 4; ++w) { S += r1[w]; SS += r2[w]; }
      pstat[blk * 2]     = S;
      pstat[blk * 2 + 1] = SS;
    }
  } else {
    const int wblk = blk - 512;
    const int which = wblk >> 5;
    const float* src = (which == 0) ? Wq : (which == 1) ? Wk : (which == 2) ? Wv : Wp;
    const int base = (wblk & 31) * 2048 + threadIdx.x * 8;
    const float4 v0 = *(const float4*)(src + base);
    const float4 v1 = *(const float4*)(src + base + 4);
    short ob[8] __attribute__((aligned(16)));
    if (which < 3) {
      ob[0] = f2bf(v0.x); ob[1] = f2bf(v0.y); ob[2] = f2bf(v0.z); ob[3] = f2bf(v0.w);
      ob[4] = f2bf(v1.x); ob[5] = f2bf(v1.y); ob[6] = f2bf(v1.z); ob[7] = f2bf(v1.w);
    } else {
      ob[0] = f2h(v0.x); ob[1] = f2h(v0.y); ob[2] = f2h(v0.z); ob[3] = f2h(v0.w);
      ob[4] = f2h(v1.x); ob[5] = f2h(v1.y); ob[6] = f2h(v1.z); ob[7] = f2h(v1.w);
    }
    const int o = base >> 8, c = base & 255;
    const int dst = (((o >> 4) * 8 + (c >> 5)) * 64 + ((c >> 3) & 3) * 16 + (o & 15)) * 8;
    *(uint4*)(wdst + which * 65536 + dst) = *(const uint4*)ob;
  }
}

// ---------------- QKV MFMA GEMM (round-14 verified body, 64-l tiles) ----------------
// grid (2, 256) ot-major: consecutive blocks share the x-tile -> L2-hit staging.
// Vo written PRE-PERMUTED per round-4 verified formula (64-l):
//   pos = l0 + 32*(n0>>1) + 8*(lq>>2) + 4*(n0&1) + (lq&3)
__global__ __launch_bounds__(256) void qkv_gemm(
    const float* __restrict__ x, const float* __restrict__ gamma,
    const float* __restrict__ beta, const float* __restrict__ pstat,
    const short* __restrict__ Wqb, const short* __restrict__ Wkb,
    const short* __restrict__ Wvb,
    short* __restrict__ Qt, short* __restrict__ Kt, _Float16* __restrict__ Vo) {
  __shared__ __align__(16) short smem[64 * 272];   // xn tile (stride 264), later qt/kt (stride 136)
  const int lt = blockIdx.y, ot2 = blockIdx.x;     // ot2 covers 128 output channels
  const int n = lt >> 6, l0 = (lt & 63) << 6;
  const int wave = threadIdx.x >> 6, lane = threadIdx.x & 63;
  const int lq = lane & 15, quad = lane >> 4;

  // ---- stage: normalize + bf16 + transpose into LDS (once per block) ----
  #pragma unroll
  for (int i = 0; i < 2; ++i) {
    const int u = threadIdx.x + i * 256;
    const int cc = u >> 4, l4 = u & 15;              // cc = c-chunk == group
    const int grp = n * NG + cc;
    float S = 0.f, SS = 0.f;
    #pragma unroll
    for (int w = 0; w < 4; ++w) {
      S  += pstat[(grp * 4 + w) * 2];
      SS += pstat[(grp * 4 + w) * 2 + 1];
    }
    const float mean = S / 32768.f;                  // NE = 8*4096
    const float rstd = rsqrtf(SS / 32768.f - mean * mean + EPSV);
    const float* xp = x + (size_t)(n * CC + cc * CPG) * LL + l0 + l4 * 4;
    short ob[4][8] __attribute__((aligned(16)));
    #pragma unroll
    for (int j = 0; j < 8; ++j) {
      const float scl = rstd * gamma[cc * CPG + j];
      const float shf = beta[cc * CPG + j] - mean * scl;
      const float4 v = *(const float4*)(xp + (size_t)j * LL);
      ob[0][j] = f2bf(v.x * scl + shf);
      ob[1][j] = f2bf(v.y * scl + shf);
      ob[2][j] = f2bf(v.z * scl + shf);
      ob[3][j] = f2bf(v.w * scl + shf);
    }
    short* dst = smem + (l4 * 4) * 264 + cc * 8;
    #pragma unroll
    for (int jj = 0; jj < 4; ++jj)
      *(uint4*)(dst + jj * 264) = *(const uint4*)ob[jj];
  }
  __syncthreads();

  // ---- MFMA K-loop: frag-major weights (coalesced), fb frags from LDS ----
  const int tb   = (ot2 * 8 + wave) * 8;             // tile base for w=0 (x512 elems)
  const int loff = lane * 8;
  const short* xl = smem + lq * 264 + quad * 8;

  const f32x4 z = {0.f, 0.f, 0.f, 0.f};
  f32x4 aq[2][4] = {{z, z, z, z}, {z, z, z, z}};
  f32x4 ak[2][4] = {{z, z, z, z}, {z, z, z, z}};
  f32x4 av[2][4] = {{z, z, z, z}, {z, z, z, z}};

  #pragma unroll
  for (int c5 = 0; c5 < 8; ++c5) {
    const int c0 = c5 * 32;
    const bf16x8 fq0 = *(const bf16x8*)(Wqb + (tb + c5) * 512 + loff);
    const bf16x8 fq1 = *(const bf16x8*)(Wqb + (tb + 32 + c5) * 512 + loff);
    const bf16x8 fk0 = *(const bf16x8*)(Wkb + (tb + c5) * 512 + loff);
    const bf16x8 fk1 = *(const bf16x8*)(Wkb + (tb + 32 + c5) * 512 + loff);
    const bf16x8 fv0 = *(const bf16x8*)(Wvb + (tb + c5) * 512 + loff);
    const bf16x8 fv1 = *(const bf16x8*)(Wvb + (tb + 32 + c5) * 512 + loff);
    #pragma unroll
    for (int n0 = 0; n0 < 4; ++n0) {
      const bf16x8 fb = *(const bf16x8*)(xl + (n0 * 16) * 264 + c0);
      aq[0][n0] = __builtin_amdgcn_mfma_f32_16x16x32_bf16(fq0, fb, aq[0][n0], 0, 0, 0);
      aq[1][n0] = __builtin_amdgcn_mfma_f32_16x16x32_bf16(fq1, fb, aq[1][n0], 0, 0, 0);
      ak[0][n0] = __builtin_amdgcn_mfma_f32_16x16x32_bf16(fk0, fb, ak[0][n0], 0, 0, 0);
      ak[1][n0] = __builtin_amdgcn_mfma_f32_16x16x32_bf16(fk1, fb, ak[1][n0], 0, 0, 0);
      av[0][n0] = __builtin_amdgcn_mfma_f32_16x16x32_bf16(fv0, fb, av[0][n0], 0, 0, 0);
      av[1][n0] = __builtin_amdgcn_mfma_f32_16x16x32_bf16(fv1, fb, av[1][n0], 0, 0, 0);
    }
  }

  // ---- V write: pre-permuted key position within the 64-block (round-4 verified) ----
  #pragma unroll
  for (int w = 0; w < 2; ++w) {
    const size_t hb = (size_t)(n * NH + ot2 * 2 + w);
    #pragma unroll
    for (int n0 = 0; n0 < 4; ++n0) {
      const int pos = l0 + 32 * (n0 >> 1) + 8 * (lq >> 2) + 4 * (n0 & 1) + (lq & 3);
      #pragma unroll
      for (int r = 0; r < 4; ++r)
        Vo[(hb * DH + wave * 16 + quad * 4 + r) * LL + pos] = (_Float16)av[w][n0][r];
    }
  }

  // ---- reuse LDS for Qt/Kt repack: [64 l][136] per tensor (16B-aligned rows) ----
  __syncthreads();                                   // all xn reads done
  short* qt_l = smem;                                // [64][136]
  short* kt_l = smem + 64 * 136;                     // [64][136]
  #pragma unroll
  for (int w = 0; w < 2; ++w)
    #pragma unroll
    for (int n0 = 0; n0 < 4; ++n0)
      #pragma unroll
      for (int r = 0; r < 4; ++r) {
        const int row = n0 * 16 + lq;
        const int col = w * 64 + wave * 16 + quad * 4 + r;
        qt_l[row * 136 + col] = f2bf(aq[w][n0][r] * SCALE_Q);
        kt_l[row * 136 + col] = f2bf(ak[w][n0][r]);
      }
  __syncthreads();
  #pragma unroll
  for (int i = 0; i < 4; ++i) {
    const int u = threadIdx.x + i * 256;
    const int row = u >> 4, ch16 = u & 15;           // 64 rows x 16 chunks of 8 ch
    const int h = ot2 * 2 + (ch16 >> 3);
    const int d0 = (ch16 & 7) * 8;
    const size_t hb = (size_t)(n * NH + h);
    *(uint4*)(Qt + (hb * LL + l0 + row) * DH + d0) = *(const uint4*)&qt_l[row * 136 + ch16 * 8];
    *(uint4*)(Kt + (hb * LL + l0 + row) * DH + d0) = *(const uint4*)&kt_l[row * 136 + ch16 * 8];
  }
}

// ---------------- MFMA flash attention: 64 q/wave, perm-Vo uint4 staging + setprio ----------------
// grid (LL/256, NH*2, NB) = 512 blocks, block 256 (4 waves), 2 waves/SIMD (proven).
// T5: setprio(1) around the pure-MFMA cluster (l-sum + PV). 2 independent
// blocks/CU give wave role-diversity -> priority lets MFMA waves win arbitration.
__global__ __launch_bounds__(256, 2) void attn_mfma_kernel(
    const short* __restrict__ Qt, const short* __restrict__ Kt,
    const _Float16* __restrict__ Vb, _Float16* __restrict__ Opart,
    float* __restrict__ lpart) {
  __shared__ __align__(16) short    k_lds[2][64 * 64];   // 8 KB each, swizzled
  __shared__ __align__(16) _Float16 v_lds[2][64 * 64];   // 8 KB each, swizzled (perm in global)

  const int t = threadIdx.x;
  const int wave = t >> 6, lane = t & 63;
  const int lq = lane & 15, quad = lane >> 4;
  const int l0 = blockIdx.x * 256;
  const int h = blockIdx.y >> 1, split = blockIdx.y & 1;
  const int n = blockIdx.z;
  const int kbase = split * 2048;
  const int R = n * NH + h;
  const size_t hb = (size_t)R * (size_t)LL * DH;
  const short* const Kp = Kt + hb;      // [key][d] bf16
  const _Float16* const Vp = Vb + hb;   // [d][perm(key)] f16

  const int qbase = l0 + wave * 64;
  bf16x8 qb[4][2];
  #pragma unroll
  for (int qf = 0; qf < 4; ++qf)
    #pragma unroll
    for (int c = 0; c < 2; ++c)
      qb[qf][c] = *(const bf16x8*)(Qt + hb + (size_t)(qbase + qf * 16 + lq) * DH + c * 32 + quad * 8);

  const f32x4 z = {0.f, 0.f, 0.f, 0.f};
  f32x4 o[4][4] = {{z, z, z, z}, {z, z, z, z}, {z, z, z, z}, {z, z, z, z}};
  f32x4 ol[4] = {z, z, z, z};

  f16x8 ones8;
  #pragma unroll
  for (int i = 0; i < 8; ++i) ones8[i] = (_Float16)1.0f;

  const int srow = t >> 3, sch = t & 7;   // staging: rows 0..31(+32), chunk 0..7

  // stage tile 0
  {
    *(uint4*)&k_lds[0][sw(srow, sch)]      = *(const uint4*)(Kp + (size_t)(kbase + srow) * DH + sch * 8);
    *(uint4*)&k_lds[0][sw(32 + srow, sch)] = *(const uint4*)(Kp + (size_t)(kbase + 32 + srow) * DH + sch * 8);
    *(uint4*)&v_lds[0][sw(srow, sch)]      = *(const uint4*)(Vp + (size_t)srow * LL + kbase + sch * 8);
    *(uint4*)&v_lds[0][sw(32 + srow, sch)] = *(const uint4*)(Vp + (size_t)(32 + srow) * LL + kbase + sch * 8);
  }
  __syncthreads();

  for (int kt = 0; kt < 32; ++kt) {
    const int cur = kt & 1;
    // prefetch next tile into regs (issue-early / write-late)
    uint4 kpre[2], vpre[2];
    if (kt < 31) {
      const int kpos = kbase + (kt + 1) * 64;
      kpre[0] = *(const uint4*)(Kp + (size_t)(kpos + srow) * DH + sch * 8);
      kpre[1] = *(const uint4*)(Kp + (size_t)(kpos + 32 + srow) * DH + sch * 8);
      vpre[0] = *(const uint4*)(Vp + (size_t)srow * LL + kpos + sch * 8);
      vpre[1] = *(const uint4*)(Vp + (size_t)(32 + srow) * LL + kpos + sch * 8);
    }
    const short* kb = k_lds[cur];
    const _Float16* vbuf = v_lds[cur];

    // ---- S^T = K·Q^T (bf16), p = exp2(s) -> f16 pack directly into A-frags ----
    union PU { f16x4 h4[2]; f16x8 h8; } af[2][4];
    #pragma unroll
    for (int mf = 0; mf < 4; ++mf) {
      const bf16x8 ka0 = *(const bf16x8*)&kb[sw(mf * 16 + lq, quad)];
      const bf16x8 ka1 = *(const bf16x8*)&kb[sw(mf * 16 + lq, 4 + quad)];
      #pragma unroll
      for (int qf = 0; qf < 4; ++qf) {
        f32x4 zz = {0.f, 0.f, 0.f, 0.f};
        zz = __builtin_amdgcn_mfma_f32_16x16x32_bf16(ka0, qb[qf][0], zz, 0, 0, 0);
        zz = __builtin_amdgcn_mfma_f32_16x16x32_bf16(ka1, qb[qf][1], zz, 0, 0, 0);
        union { h16x2 h2[2]; f16x4 h4; } u;
        u.h2[0] = __builtin_amdgcn_cvt_pkrtz(__builtin_amdgcn_exp2f(zz[0]),
                                             __builtin_amdgcn_exp2f(zz[1]));
        u.h2[1] = __builtin_amdgcn_cvt_pkrtz(__builtin_amdgcn_exp2f(zz[2]),
                                             __builtin_amdgcn_exp2f(zz[3]));
        af[mf >> 1][qf].h4[mf & 1] = u.h4;
      }
    }

    // ---- pure-MFMA cluster under elevated priority (T5) ----
    __builtin_amdgcn_s_setprio(1);
    // l-sum via ones-MFMA: D rows == o rows, in-lane
    #pragma unroll
    for (int qf = 0; qf < 4; ++qf) {
      ol[qf] = __builtin_amdgcn_mfma_f32_16x16x32_f16(af[0][qf].h8, ones8, ol[qf], 0, 0, 0);
      ol[qf] = __builtin_amdgcn_mfma_f32_16x16x32_f16(af[1][qf].h8, ones8, ol[qf], 0, 0, 0);
    }
    // O += P·V: b128 V-frags, 0-conflict pattern
    #pragma unroll
    for (int df = 0; df < 4; ++df)
      #pragma unroll
      for (int cc = 0; cc < 2; ++cc) {
        const f16x8 vb8 = *(const f16x8*)&vbuf[sw(df * 16 + lq, cc * 4 + quad)];
        #pragma unroll
        for (int qf = 0; qf < 4; ++qf)
          o[qf][df] = __builtin_amdgcn_mfma_f32_16x16x32_f16(af[cc][qf].h8, vb8, o[qf][df], 0, 0, 0);
      }
    __builtin_amdgcn_s_setprio(0);

    // ---- write prefetched tile to other buffer ----
    if (kt < 31) {
      const int nxt = 1 - cur;
      *(uint4*)&k_lds[nxt][sw(srow, sch)]      = kpre[0];
      *(uint4*)&k_lds[nxt][sw(32 + srow, sch)] = kpre[1];
      *(uint4*)&v_lds[nxt][sw(srow, sch)]      = vpre[0];
      *(uint4*)&v_lds[nxt][sw(32 + srow, sch)] = vpre[1];
      __syncthreads();
    }
  }

  // ---- epilogue: store partial l (rows match in-lane) + raw fp16 partial O ----
  const size_t pb = ((size_t)split * 16 + R) * (size_t)LL * DH;
  #pragma unroll
  for (int qf = 0; qf < 4; ++qf) {
    if (lq == 0) {
      #pragma unroll
      for (int r = 0; r < 4; ++r)
        lpart[((size_t)split * 16 + R) * LL + qbase + qf * 16 + quad * 4 + r] = ol[qf][r];
    }
    #pragma unroll
    for (int df = 0; df < 4; ++df)
      #pragma unroll
      for (int r = 0; r < 4; ++r) {
        const int q = qbase + qf * 16 + quad * 4 + r;
        Opart[pb + (size_t)q * DH + df * 16 + lq] = (_Float16)o[qf][df][r];
      }
  }
}

// ---------------- output projection (round-14 verified body): LDS-staged shared B ----------------
// grid (2, 256) ot-major. fb (normalized O) is IDENTICAL for all 4 waves -> stage
// it once per block per head into LDS, double-buffered across the 4 heads.
__global__ __launch_bounds__(256) void proj_gemm(
    const _Float16* __restrict__ Opart, const float* __restrict__ lpart,
    const _Float16* __restrict__ Wpf, const float* __restrict__ bp,
    float* __restrict__ out) {
  __shared__ __align__(16) _Float16 fb_lds[2][64 * 64];  // 8 KB each, sw()-swizzled
  const int lt = blockIdx.y, ot2 = blockIdx.x;   // ot2 covers 128 output channels
  const int n = lt >> 6, l0 = (lt & 63) << 6;
  const int wave = threadIdx.x >> 6, lane = threadIdx.x & 63;
  const int lq = lane & 15, quad = lane >> 4;
  const int t = threadIdx.x;
  const int qr = t >> 3, ch = t & 7;             // staging: q-row 0..31(+32), d-chunk 0..7

  const int tb   = (ot2 * 8 + wave) * 8;         // frag tile base for w=0
  const int loff = lane * 8;

  // stage head h into buf: fb = (b0 + b1) * (f16)(1/l)
  auto stage = [&](int buf, int h) {
    const _Float16* Op = Opart + ((size_t)(n * NH + h) * LL + l0) * DH;
    #pragma unroll
    for (int half = 0; half < 2; ++half) {
      const int q = half * 32 + qr;
      const size_t rr = (size_t)(n * NH + h) * LL + l0 + q;
      const _Float16 il = (_Float16)(1.0f / (lpart[rr] + lpart[rr + 16 * (size_t)LL]));
      const size_t e = (size_t)q * DH + ch * 8;
      const f16x8 b0 = *(const f16x8*)(Op + e);
      const f16x8 b1 = *(const f16x8*)(Op + e + (size_t)PSPLIT);
      f16x8 sc8;
      #pragma unroll
      for (int i = 0; i < 8; ++i) sc8[i] = il;
      const f16x8 fbn = (b0 + b1) * sc8;
      *(f16x8*)&fb_lds[buf][sw(q, ch)] = fbn;
    }
  };

  stage(0, 0);
  __syncthreads();

  const f32x4 z = {0.f, 0.f, 0.f, 0.f};
  f32x4 acc[2][4] = {{z, z, z, z}, {z, z, z, z}};
  for (int h = 0; h < NH; ++h) {
    const int cur = h & 1;
    // prefetch next head into regs (issue-early), write-late after compute
    f16x8 pre[2];
    if (h < NH - 1) {
      const _Float16* Op = Opart + ((size_t)(n * NH + h + 1) * LL + l0) * DH;
      #pragma unroll
      for (int half = 0; half < 2; ++half) {
        const int q = half * 32 + qr;
        const size_t rr = (size_t)(n * NH + h + 1) * LL + l0 + q;
        const _Float16 il = (_Float16)(1.0f / (lpart[rr] + lpart[rr + 16 * (size_t)LL]));
        const size_t e = (size_t)q * DH + ch * 8;
        const f16x8 b0 = *(const f16x8*)(Op + e);
        const f16x8 b1 = *(const f16x8*)(Op + e + (size_t)PSPLIT);
        f16x8 sc8;
        #pragma unroll
        for (int i = 0; i < 8; ++i) sc8[i] = il;
        pre[half] = (b0 + b1) * sc8;
      }
    }
    // compute the two c5 slices of this head from LDS
    #pragma unroll
    for (int cw = 0; cw < 2; ++cw) {
      const int c5 = 2 * h + cw;
      const int c_idx = cw * 4 + quad;
      const f16x8 fa0 = *(const f16x8*)(Wpf + (tb + c5) * 512 + loff);
      const f16x8 fa1 = *(const f16x8*)(Wpf + (tb + 32 + c5) * 512 + loff);
      #pragma unroll
      for (int n0 = 0; n0 < 4; ++n0) {
        const f16x8 fb = *(const f16x8*)&fb_lds[cur][sw(n0 * 16 + lq, c_idx)];
        acc[0][n0] = __builtin_amdgcn_mfma_f32_16x16x32_f16(fa0, fb, acc[0][n0], 0, 0, 0);
        acc[1][n0] = __builtin_amdgcn_mfma_f32_16x16x32_f16(fa1, fb, acc[1][n0], 0, 0, 0);
      }
    }
    if (h < NH - 1) {
      #pragma unroll
      for (int half = 0; half < 2; ++half)
        *(f16x8*)&fb_lds[cur ^ 1][sw(half * 32 + qr, ch)] = pre[half];
      __syncthreads();
    }
  }

  #pragma unroll
  for (int w = 0; w < 2; ++w)
    #pragma unroll
    for (int r = 0; r < 4; ++r) {
      const int oo = ot2 * 128 + w * 64 + wave * 16 + quad * 4 + r;
      const float bias = bp[oo];
      #pragma unroll
      for (int n0 = 0; n0 < 4; ++n0)
        out[((size_t)n * CC + oo) * LL + l0 + n0 * 16 + lq] = acc[w][n0][r] + bias;
    }
}

extern "C" void kernel_launch(void* const* d_in, const int* in_sizes, int n_in,
                              void* d_out, int out_size, void* d_ws, size_t ws_size,
                              hipStream_t stream) {
  const float* x     = (const float*)d_in[0];
  const float* gamma = (const float*)d_in[1];
  const float* beta  = (const float*)d_in[2];
  const float* Wq    = (const float*)d_in[3];
  const float* Wk    = (const float*)d_in[4];
  const float* Wv    = (const float*)d_in[5];
  const float* Wp    = (const float*)d_in[6];
  const float* bp    = (const float*)d_in[7];
  float* out = (float*)d_out;

  const size_t S = (size_t)NB * CC * LL;  // 4,194,304
  short*     Qt  = (short*)d_ws;          // bf16 [n,h][l][d]
  short*     Kt  = Qt + S;
  _Float16*  Vo  = (_Float16*)(Kt + S);   // f16 [n,h][d][perm(l)]
  short*     Wb  = (short*)(Vo + S);      // 4 x 65536 (bf16 x3, f16 x1), frag-major
  _Float16*  Opart = (_Float16*)(Wb + 4 * 65536);  // 2 x 8 MB fp16
  float*     lpart = (float*)(Opart + 2 * (size_t)PSPLIT); // 2 x 256 KB fp32
  float*     pstat = lpart + 2 * 16 * (size_t)LL;  // 1024 floats GN partials

  gnstats_wcvt<<<640,                 256, 0, stream>>>(x, pstat, Wq, Wk, Wv, Wp, Wb);
  qkv_gemm   <<<dim3(2, 256),         256, 0, stream>>>(x, gamma, beta, pstat,
                 Wb, Wb + 65536, Wb + 131072, Qt, Kt, Vo);
  attn_mfma_kernel<<<dim3(LL/256, NH*2, NB), 256, 0, stream>>>(Qt, Kt, Vo, Opart, lpart);
  proj_gemm  <<<dim3(2, 256),         256, 0, stream>>>(Opart, lpart,
                 (const _Float16*)(Wb + 196608), bp, out);
}

// Round 17
// 169.208 us; speedup vs baseline: 1.0260x; 1.0011x over previous
//
#include <hip/hip_runtime.h>
#include <cstddef>
#include <cstdint>

#define NB 4
#define CC 256
#define LL 4096
#define NG 32
#define CPG 8
#define NH 4
#define DH 64
#define PSPLIT 4194304   // fp16 partial-O elements per split: 16*4096*64

static constexpr float EPSV  = 1e-5f;
static constexpr float SCALE_Q = 0.125f * 1.4426950408889634f; // dh^-0.5 * log2(e)

typedef __attribute__((ext_vector_type(8))) short bf16x8;
typedef __attribute__((ext_vector_type(4))) float f32x4;
typedef _Float16 f16x8 __attribute__((ext_vector_type(8)));
typedef _Float16 f16x4 __attribute__((ext_vector_type(4)));
typedef __fp16  h16x2 __attribute__((ext_vector_type(2)));   // cvt_pkrtz native type

__device__ __forceinline__ short f2bf(float f) {
  unsigned u = __float_as_uint(f);
  unsigned r = (u + 0x7fffu + ((u >> 16) & 1u)) >> 16;
  return (short)r;
}
__device__ __forceinline__ short f2h(float f) {
  union { _Float16 h; short s; } u;
  u.h = (_Float16)f;
  return u.s;
}
// element offset of 16B chunk (8 elems) with XOR swizzle: row stride 64 elems
__device__ __forceinline__ int sw(int row, int chunk) {
  return row * 64 + ((chunk ^ (row & 7)) * 8);
}

// ---------------- fused GroupNorm stats (512 blocks) + weight cvt (128 blocks) ----------------
// wcvt emits FRAGMENT-MAJOR layout: tile t = o/16, c5 = c/32; element at
// ((t*8+c5)*64 + quad*16 + row)*8 + e. A-frag load = one 1KB wave transaction.
__global__ __launch_bounds__(256) void gnstats_wcvt(
    const float* __restrict__ x, float* __restrict__ pstat,
    const float* __restrict__ Wq, const float* __restrict__ Wk,
    const float* __restrict__ Wv, const float* __restrict__ Wp,
    short* __restrict__ wdst) {
  __shared__ float r1[4], r2[4];
  const int blk = blockIdx.x;
  if (blk < 512) {
    const int grp = blk >> 2, qtr = blk & 3;          // grp = n*32+g
    const float* xp = x + (size_t)grp * CPG * LL + qtr * 1024 + threadIdx.x * 4;
    float s = 0.f, ss = 0.f;
    #pragma unroll
    for (int cc = 0; cc < 8; ++cc) {
      const float4 v = *(const float4*)(xp + (size_t)cc * LL);
      s  += v.x + v.y + v.z + v.w;
      ss += v.x * v.x + v.y * v.y + v.z * v.z + v.w * v.w;
    }
    #pragma unroll
    for (int off = 32; off; off >>= 1) {
      s  += __shfl_down(s, off);
      ss += __shfl_down(ss, off);
    }
    const int wid = threadIdx.x >> 6, lane = threadIdx.x & 63;
    if (lane == 0) { r1[wid] = s; r2[wid] = ss; }
    __syncthreads();
    if (threadIdx.x == 0) {
      float S = 0.f, SS = 0.f;
      #pragma unroll
      for (int w = 0; w < 4; ++w) { S += r1[w]; SS += r2[w]; }
      pstat[blk * 2]     = S;
      pstat[blk * 2 + 1] = SS;
    }
  } else {
    const int wblk = blk - 512;
    const int which = wblk >> 5;
    const float* src = (which == 0) ? Wq : (which == 1) ? Wk : (which == 2) ? Wv : Wp;
    const int base = (wblk & 31) * 2048 + threadIdx.x * 8;
    const float4 v0 = *(const float4*)(src + base);
    const float4 v1 = *(const float4*)(src + base + 4);
    short ob[8] __attribute__((aligned(16)));
    if (which < 3) {
      ob[0] = f2bf(v0.x); ob[1] = f2bf(v0.y); ob[2] = f2bf(v0.z); ob[3] = f2bf(v0.w);
      ob[4] = f2bf(v1.x); ob[5] = f2bf(v1.y); ob[6] = f2bf(v1.z); ob[7] = f2bf(v1.w);
    } else {
      ob[0] = f2h(v0.x); ob[1] = f2h(v0.y); ob[2] = f2h(v0.z); ob[3] = f2h(v0.w);
      ob[4] = f2h(v1.x); ob[5] = f2h(v1.y); ob[6] = f2h(v1.z); ob[7] = f2h(v1.w);
    }
    const int o = base >> 8, c = base & 255;
    const int dst = (((o >> 4) * 8 + (c >> 5)) * 64 + ((c >> 3) & 3) * 16 + (o & 15)) * 8;
    *(uint4*)(wdst + which * 65536 + dst) = *(const uint4*)ob;
  }
}

// ---------------- QKV MFMA GEMM (round-14 verified body, 64-l tiles) ----------------
// grid (2, 256) ot-major: consecutive blocks share the x-tile -> L2-hit staging.
// Vo written PRE-PERMUTED per round-4 verified formula (64-l):
//   pos = l0 + 32*(n0>>1) + 8*(lq>>2) + 4*(n0&1) + (lq&3)
__global__ __launch_bounds__(256) void qkv_gemm(
    const float* __restrict__ x, const float* __restrict__ gamma,
    const float* __restrict__ beta, const float* __restrict__ pstat,
    const short* __restrict__ Wqb, const short* __restrict__ Wkb,
    const short* __restrict__ Wvb,
    short* __restrict__ Qt, short* __restrict__ Kt, _Float16* __restrict__ Vo) {
  __shared__ __align__(16) short smem[64 * 272];   // xn tile (stride 264), later qt/kt (stride 136)
  const int lt = blockIdx.y, ot2 = blockIdx.x;     // ot2 covers 128 output channels
  const int n = lt >> 6, l0 = (lt & 63) << 6;
  const int wave = threadIdx.x >> 6, lane = threadIdx.x & 63;
  const int lq = lane & 15, quad = lane >> 4;

  // ---- stage: normalize + bf16 + transpose into LDS (once per block) ----
  #pragma unroll
  for (int i = 0; i < 2; ++i) {
    const int u = threadIdx.x + i * 256;
    const int cc = u >> 4, l4 = u & 15;              // cc = c-chunk == group
    const int grp = n * NG + cc;
    float S = 0.f, SS = 0.f;
    #pragma unroll
    for (int w = 0; w < 4; ++w) {
      S  += pstat[(grp * 4 + w) * 2];
      SS += pstat[(grp * 4 + w) * 2 + 1];
    }
    const float mean = S / 32768.f;                  // NE = 8*4096
    const float rstd = rsqrtf(SS / 32768.f - mean * mean + EPSV);
    const float* xp = x + (size_t)(n * CC + cc * CPG) * LL + l0 + l4 * 4;
    short ob[4][8] __attribute__((aligned(16)));
    #pragma unroll
    for (int j = 0; j < 8; ++j) {
      const float scl = rstd * gamma[cc * CPG + j];
      const float shf = beta[cc * CPG + j] - mean * scl;
      const float4 v = *(const float4*)(xp + (size_t)j * LL);
      ob[0][j] = f2bf(v.x * scl + shf);
      ob[1][j] = f2bf(v.y * scl + shf);
      ob[2][j] = f2bf(v.z * scl + shf);
      ob[3][j] = f2bf(v.w * scl + shf);
    }
    short* dst = smem + (l4 * 4) * 264 + cc * 8;
    #pragma unroll
    for (int jj = 0; jj < 4; ++jj)
      *(uint4*)(dst + jj * 264) = *(const uint4*)ob[jj];
  }
  __syncthreads();

  // ---- MFMA K-loop: frag-major weights (coalesced), fb frags from LDS ----
  const int tb   = (ot2 * 8 + wave) * 8;             // tile base for w=0 (x512 elems)
  const int loff = lane * 8;
  const short* xl = smem + lq * 264 + quad * 8;

  const f32x4 z = {0.f, 0.f, 0.f, 0.f};
  f32x4 aq[2][4] = {{z, z, z, z}, {z, z, z, z}};
  f32x4 ak[2][4] = {{z, z, z, z}, {z, z, z, z}};
  f32x4 av[2][4] = {{z, z, z, z}, {z, z, z, z}};

  #pragma unroll
  for (int c5 = 0; c5 < 8; ++c5) {
    const int c0 = c5 * 32;
    const bf16x8 fq0 = *(const bf16x8*)(Wqb + (tb + c5) * 512 + loff);
    const bf16x8 fq1 = *(const bf16x8*)(Wqb + (tb + 32 + c5) * 512 + loff);
    const bf16x8 fk0 = *(const bf16x8*)(Wkb + (tb + c5) * 512 + loff);
    const bf16x8 fk1 = *(const bf16x8*)(Wkb + (tb + 32 + c5) * 512 + loff);
    const bf16x8 fv0 = *(const bf16x8*)(Wvb + (tb + c5) * 512 + loff);
    const bf16x8 fv1 = *(const bf16x8*)(Wvb + (tb + 32 + c5) * 512 + loff);
    #pragma unroll
    for (int n0 = 0; n0 < 4; ++n0) {
      const bf16x8 fb = *(const bf16x8*)(xl + (n0 * 16) * 264 + c0);
      aq[0][n0] = __builtin_amdgcn_mfma_f32_16x16x32_bf16(fq0, fb, aq[0][n0], 0, 0, 0);
      aq[1][n0] = __builtin_amdgcn_mfma_f32_16x16x32_bf16(fq1, fb, aq[1][n0], 0, 0, 0);
      ak[0][n0] = __builtin_amdgcn_mfma_f32_16x16x32_bf16(fk0, fb, ak[0][n0], 0, 0, 0);
      ak[1][n0] = __builtin_amdgcn_mfma_f32_16x16x32_bf16(fk1, fb, ak[1][n0], 0, 0, 0);
      av[0][n0] = __builtin_amdgcn_mfma_f32_16x16x32_bf16(fv0, fb, av[0][n0], 0, 0, 0);
      av[1][n0] = __builtin_amdgcn_mfma_f32_16x16x32_bf16(fv1, fb, av[1][n0], 0, 0, 0);
    }
  }

  // ---- V write: pre-permuted key position within the 64-block (round-4 verified) ----
  #pragma unroll
  for (int w = 0; w < 2; ++w) {
    const size_t hb = (size_t)(n * NH + ot2 * 2 + w);
    #pragma unroll
    for (int n0 = 0; n0 < 4; ++n0) {
      const int pos = l0 + 32 * (n0 >> 1) + 8 * (lq >> 2) + 4 * (n0 & 1) + (lq & 3);
      #pragma unroll
      for (int r = 0; r < 4; ++r)
        Vo[(hb * DH + wave * 16 + quad * 4 + r) * LL + pos] = (_Float16)av[w][n0][r];
    }
  }

  // ---- reuse LDS for Qt/Kt repack: [64 l][136] per tensor (16B-aligned rows) ----
  __syncthreads();                                   // all xn reads done
  short* qt_l = smem;                                // [64][136]
  short* kt_l = smem + 64 * 136;                     // [64][136]
  #pragma unroll
  for (int w = 0; w < 2; ++w)
    #pragma unroll
    for (int n0 = 0; n0 < 4; ++n0)
      #pragma unroll
      for (int r = 0; r < 4; ++r) {
        const int row = n0 * 16 + lq;
        const int col = w * 64 + wave * 16 + quad * 4 + r;
        qt_l[row * 136 + col] = f2bf(aq[w][n0][r] * SCALE_Q);
        kt_l[row * 136 + col] = f2bf(ak[w][n0][r]);
      }
  __syncthreads();
  #pragma unroll
  for (int i = 0; i < 4; ++i) {
    const int u = threadIdx.x + i * 256;
    const int row = u >> 4, ch16 = u & 15;           // 64 rows x 16 chunks of 8 ch
    const int h = ot2 * 2 + (ch16 >> 3);
    const int d0 = (ch16 & 7) * 8;
    const size_t hb = (size_t)(n * NH + h);
    *(uint4*)(Qt + (hb * LL + l0 + row) * DH + d0) = *(const uint4*)&qt_l[row * 136 + ch16 * 8];
    *(uint4*)(Kt + (hb * LL + l0 + row) * DH + d0) = *(const uint4*)&kt_l[row * 136 + ch16 * 8];
  }
}

// ---------------- MFMA flash attention: 64 q/wave, perm-Vo uint4 staging ----------------
// grid (LL/256, NH*2, NB) = 512 blocks, block 256 (4 waves), 2 waves/SIMD (proven).
// Vo pre-permuted by qkv -> V staging is single uint4 per row, reproducing the
// round-0 LDS image exactly; all frag reads unchanged. (round-14 verified body,
// setprio removed: r16 showed it perturbs codegen VGPR 116->96 and costs +4us)
__global__ __launch_bounds__(256, 2) void attn_mfma_kernel(
    const short* __restrict__ Qt, const short* __restrict__ Kt,
    const _Float16* __restrict__ Vb, _Float16* __restrict__ Opart,
    float* __restrict__ lpart) {
  __shared__ __align__(16) short    k_lds[2][64 * 64];   // 8 KB each, swizzled
  __shared__ __align__(16) _Float16 v_lds[2][64 * 64];   // 8 KB each, swizzled (perm in global)

  const int t = threadIdx.x;
  const int wave = t >> 6, lane = t & 63;
  const int lq = lane & 15, quad = lane >> 4;
  const int l0 = blockIdx.x * 256;
  const int h = blockIdx.y >> 1, split = blockIdx.y & 1;
  const int n = blockIdx.z;
  const int kbase = split * 2048;
  const int R = n * NH + h;
  const size_t hb = (size_t)R * (size_t)LL * DH;
  const short* const Kp = Kt + hb;      // [key][d] bf16
  const _Float16* const Vp = Vb + hb;   // [d][perm(key)] f16

  const int qbase = l0 + wave * 64;
  bf16x8 qb[4][2];
  #pragma unroll
  for (int qf = 0; qf < 4; ++qf)
    #pragma unroll
    for (int c = 0; c < 2; ++c)
      qb[qf][c] = *(const bf16x8*)(Qt + hb + (size_t)(qbase + qf * 16 + lq) * DH + c * 32 + quad * 8);

  const f32x4 z = {0.f, 0.f, 0.f, 0.f};
  f32x4 o[4][4] = {{z, z, z, z}, {z, z, z, z}, {z, z, z, z}, {z, z, z, z}};
  f32x4 ol[4] = {z, z, z, z};

  f16x8 ones8;
  #pragma unroll
  for (int i = 0; i < 8; ++i) ones8[i] = (_Float16)1.0f;

  const int srow = t >> 3, sch = t & 7;   // staging: rows 0..31(+32), chunk 0..7

  // stage tile 0
  {
    *(uint4*)&k_lds[0][sw(srow, sch)]      = *(const uint4*)(Kp + (size_t)(kbase + srow) * DH + sch * 8);
    *(uint4*)&k_lds[0][sw(32 + srow, sch)] = *(const uint4*)(Kp + (size_t)(kbase + 32 + srow) * DH + sch * 8);
    *(uint4*)&v_lds[0][sw(srow, sch)]      = *(const uint4*)(Vp + (size_t)srow * LL + kbase + sch * 8);
    *(uint4*)&v_lds[0][sw(32 + srow, sch)] = *(const uint4*)(Vp + (size_t)(32 + srow) * LL + kbase + sch * 8);
  }
  __syncthreads();

  for (int kt = 0; kt < 32; ++kt) {
    const int cur = kt & 1;
    // prefetch next tile into regs (issue-early / write-late)
    uint4 kpre[2], vpre[2];
    if (kt < 31) {
      const int kpos = kbase + (kt + 1) * 64;
      kpre[0] = *(const uint4*)(Kp + (size_t)(kpos + srow) * DH + sch * 8);
      kpre[1] = *(const uint4*)(Kp + (size_t)(kpos + 32 + srow) * DH + sch * 8);
      vpre[0] = *(const uint4*)(Vp + (size_t)srow * LL + kpos + sch * 8);
      vpre[1] = *(const uint4*)(Vp + (size_t)(32 + srow) * LL + kpos + sch * 8);
    }
    const short* kb = k_lds[cur];
    const _Float16* vbuf = v_lds[cur];

    // ---- S^T = K·Q^T (bf16), p = exp2(s) -> f16 pack directly into A-frags ----
    union PU { f16x4 h4[2]; f16x8 h8; } af[2][4];
    #pragma unroll
    for (int mf = 0; mf < 4; ++mf) {
      const bf16x8 ka0 = *(const bf16x8*)&kb[sw(mf * 16 + lq, quad)];
      const bf16x8 ka1 = *(const bf16x8*)&kb[sw(mf * 16 + lq, 4 + quad)];
      #pragma unroll
      for (int qf = 0; qf < 4; ++qf) {
        f32x4 zz = {0.f, 0.f, 0.f, 0.f};
        zz = __builtin_amdgcn_mfma_f32_16x16x32_bf16(ka0, qb[qf][0], zz, 0, 0, 0);
        zz = __builtin_amdgcn_mfma_f32_16x16x32_bf16(ka1, qb[qf][1], zz, 0, 0, 0);
        union { h16x2 h2[2]; f16x4 h4; } u;
        u.h2[0] = __builtin_amdgcn_cvt_pkrtz(__builtin_amdgcn_exp2f(zz[0]),
                                             __builtin_amdgcn_exp2f(zz[1]));
        u.h2[1] = __builtin_amdgcn_cvt_pkrtz(__builtin_amdgcn_exp2f(zz[2]),
                                             __builtin_amdgcn_exp2f(zz[3]));
        af[mf >> 1][qf].h4[mf & 1] = u.h4;
      }
    }

    // ---- l-sum via ones-MFMA: D rows == o rows, in-lane ----
    #pragma unroll
    for (int qf = 0; qf < 4; ++qf) {
      ol[qf] = __builtin_amdgcn_mfma_f32_16x16x32_f16(af[0][qf].h8, ones8, ol[qf], 0, 0, 0);
      ol[qf] = __builtin_amdgcn_mfma_f32_16x16x32_f16(af[1][qf].h8, ones8, ol[qf], 0, 0, 0);
    }

    // ---- O += P·V: b128 V-frags, 0-conflict pattern ----
    #pragma unroll
    for (int df = 0; df < 4; ++df)
      #pragma unroll
      for (int cc = 0; cc < 2; ++cc) {
        const f16x8 vb8 = *(const f16x8*)&vbuf[sw(df * 16 + lq, cc * 4 + quad)];
        #pragma unroll
        for (int qf = 0; qf < 4; ++qf)
          o[qf][df] = __builtin_amdgcn_mfma_f32_16x16x32_f16(af[cc][qf].h8, vb8, o[qf][df], 0, 0, 0);
      }

    // ---- write prefetched tile to other buffer ----
    if (kt < 31) {
      const int nxt = 1 - cur;
      *(uint4*)&k_lds[nxt][sw(srow, sch)]      = kpre[0];
      *(uint4*)&k_lds[nxt][sw(32 + srow, sch)] = kpre[1];
      *(uint4*)&v_lds[nxt][sw(srow, sch)]      = vpre[0];
      *(uint4*)&v_lds[nxt][sw(32 + srow, sch)] = vpre[1];
      __syncthreads();
    }
  }

  // ---- epilogue: store partial l (rows match in-lane) + raw fp16 partial O ----
  const size_t pb = ((size_t)split * 16 + R) * (size_t)LL * DH;
  #pragma unroll
  for (int qf = 0; qf < 4; ++qf) {
    if (lq == 0) {
      #pragma unroll
      for (int r = 0; r < 4; ++r)
        lpart[((size_t)split * 16 + R) * LL + qbase + qf * 16 + quad * 4 + r] = ol[qf][r];
    }
    #pragma unroll
    for (int df = 0; df < 4; ++df)
      #pragma unroll
      for (int r = 0; r < 4; ++r) {
        const int q = qbase + qf * 16 + quad * 4 + r;
        Opart[pb + (size_t)q * DH + df * 16 + lq] = (_Float16)o[qf][df][r];
      }
  }
}

// ---------------- output projection (round-14 verified body): LDS-staged shared B ----------------
// grid (2, 256) ot-major. fb (normalized O) is IDENTICAL for all 4 waves -> stage
// it once per block per head into LDS, double-buffered across the 4 heads.
__global__ __launch_bounds__(256) void proj_gemm(
    const _Float16* __restrict__ Opart, const float* __restrict__ lpart,
    const _Float16* __restrict__ Wpf, const float* __restrict__ bp,
    float* __restrict__ out) {
  __shared__ __align__(16) _Float16 fb_lds[2][64 * 64];  // 8 KB each, sw()-swizzled
  const int lt = blockIdx.y, ot2 = blockIdx.x;   // ot2 covers 128 output channels
  const int n = lt >> 6, l0 = (lt & 63) << 6;
  const int wave = threadIdx.x >> 6, lane = threadIdx.x & 63;
  const int lq = lane & 15, quad = lane >> 4;
  const int t = threadIdx.x;
  const int qr = t >> 3, ch = t & 7;             // staging: q-row 0..31(+32), d-chunk 0..7

  const int tb   = (ot2 * 8 + wave) * 8;         // frag tile base for w=0
  const int loff = lane * 8;

  // stage head h into buf: fb = (b0 + b1) * (f16)(1/l)
  auto stage = [&](int buf, int h) {
    const _Float16* Op = Opart + ((size_t)(n * NH + h) * LL + l0) * DH;
    #pragma unroll
    for (int half = 0; half < 2; ++half) {
      const int q = half * 32 + qr;
      const size_t rr = (size_t)(n * NH + h) * LL + l0 + q;
      const _Float16 il = (_Float16)(1.0f / (lpart[rr] + lpart[rr + 16 * (size_t)LL]));
      const size_t e = (size_t)q * DH + ch * 8;
      const f16x8 b0 = *(const f16x8*)(Op + e);
      const f16x8 b1 = *(const f16x8*)(Op + e + (size_t)PSPLIT);
      f16x8 sc8;
      #pragma unroll
      for (int i = 0; i < 8; ++i) sc8[i] = il;
      const f16x8 fbn = (b0 + b1) * sc8;
      *(f16x8*)&fb_lds[buf][sw(q, ch)] = fbn;
    }
  };

  stage(0, 0);
  __syncthreads();

  const f32x4 z = {0.f, 0.f, 0.f, 0.f};
  f32x4 acc[2][4] = {{z, z, z, z}, {z, z, z, z}};
  for (int h = 0; h < NH; ++h) {
    const int cur = h & 1;
    // prefetch next head into regs (issue-early), write-late after compute
    f16x8 pre[2];
    if (h < NH - 1) {
      const _Float16* Op = Opart + ((size_t)(n * NH + h + 1) * LL + l0) * DH;
      #pragma unroll
      for (int half = 0; half < 2; ++half) {
        const int q = half * 32 + qr;
        const size_t rr = (size_t)(n * NH + h + 1) * LL + l0 + q;
        const _Float16 il = (_Float16)(1.0f / (lpart[rr] + lpart[rr + 16 * (size_t)LL]));
        const size_t e = (size_t)q * DH + ch * 8;
        const f16x8 b0 = *(const f16x8*)(Op + e);
        const f16x8 b1 = *(const f16x8*)(Op + e + (size_t)PSPLIT);
        f16x8 sc8;
        #pragma unroll
        for (int i = 0; i < 8; ++i) sc8[i] = il;
        pre[half] = (b0 + b1) * sc8;
      }
    }
    // compute the two c5 slices of this head from LDS
    #pragma unroll
    for (int cw = 0; cw < 2; ++cw) {
      const int c5 = 2 * h + cw;
      const int c_idx = cw * 4 + quad;
      const f16x8 fa0 = *(const f16x8*)(Wpf + (tb + c5) * 512 + loff);
      const f16x8 fa1 = *(const f16x8*)(Wpf + (tb + 32 + c5) * 512 + loff);
      #pragma unroll
      for (int n0 = 0; n0 < 4; ++n0) {
        const f16x8 fb = *(const f16x8*)&fb_lds[cur][sw(n0 * 16 + lq, c_idx)];
        acc[0][n0] = __builtin_amdgcn_mfma_f32_16x16x32_f16(fa0, fb, acc[0][n0], 0, 0, 0);
        acc[1][n0] = __builtin_amdgcn_mfma_f32_16x16x32_f16(fa1, fb, acc[1][n0], 0, 0, 0);
      }
    }
    if (h < NH - 1) {
      #pragma unroll
      for (int half = 0; half < 2; ++half)
        *(f16x8*)&fb_lds[cur ^ 1][sw(half * 32 + qr, ch)] = pre[half];
      __syncthreads();
    }
  }

  #pragma unroll
  for (int w = 0; w < 2; ++w)
    #pragma unroll
    for (int r = 0; r < 4; ++r) {
      const int oo = ot2 * 128 + w * 64 + wave * 16 + quad * 4 + r;
      const float bias = bp[oo];
      #pragma unroll
      for (int n0 = 0; n0 < 4; ++n0)
        out[((size_t)n * CC + oo) * LL + l0 + n0 * 16 + lq] = acc[w][n0][r] + bias;
    }
}

extern "C" void kernel_launch(void* const* d_in, const int* in_sizes, int n_in,
                              void* d_out, int out_size, void* d_ws, size_t ws_size,
                              hipStream_t stream) {
  const float* x     = (const float*)d_in[0];
  const float* gamma = (const float*)d_in[1];
  const float* beta  = (const float*)d_in[2];
  const float* Wq    = (const float*)d_in[3];
  const float* Wk    = (const float*)d_in[4];
  const float* Wv    = (const float*)d_in[5];
  const float* Wp    = (const float*)d_in[6];
  const float* bp    = (const float*)d_in[7];
  float* out = (float*)d_out;

  const size_t S = (size_t)NB * CC * LL;  // 4,194,304
  short*     Qt  = (short*)d_ws;          // bf16 [n,h][l][d]
  short*     Kt  = Qt + S;
  _Float16*  Vo  = (_Float16*)(Kt + S);   // f16 [n,h][d][perm(l)]
  short*     Wb  = (short*)(Vo + S);      // 4 x 65536 (bf16 x3, f16 x1), frag-major
  _Float16*  Opart = (_Float16*)(Wb + 4 * 65536);  // 2 x 8 MB fp16
  float*     lpart = (float*)(Opart + 2 * (size_t)PSPLIT); // 2 x 256 KB fp32
  float*     pstat = lpart + 2 * 16 * (size_t)LL;  // 1024 floats GN partials

  gnstats_wcvt<<<640,                 256, 0, stream>>>(x, pstat, Wq, Wk, Wv, Wp, Wb);
  qkv_gemm   <<<dim3(2, 256),         256, 0, stream>>>(x, gamma, beta, pstat,
                 Wb, Wb + 65536, Wb + 131072, Qt, Kt, Vo);
  attn_mfma_kernel<<<dim3(LL/256, NH*2, NB), 256, 0, stream>>>(Qt, Kt, Vo, Opart, lpart);
  proj_gemm  <<<dim3(2, 256),         256, 0, stream>>>(Opart, lpart,
                 (const _Float16*)(Wb + 196608), bp, out);
}